// Round 1
// baseline (1070.105 us; speedup 1.0000x reference)
//
#include <hip/hip_runtime.h>
#include <math.h>

// ---------------------------------------------------------------------------
// TopologyAwareGATEncoder: 3x GATConv(+ELU+LN) -> concat role emb -> 2-layer MLP
// N=50000, E=400000 (+N self loops), IN=64, HID=64, HEADS=4
// ---------------------------------------------------------------------------

#define WAVE 64

// ---------------- CSR build ----------------
__global__ void k_count(const int* __restrict__ ei, int* __restrict__ deg,
                        int N, int E, int E2) {
    int i = blockIdx.x * 256 + threadIdx.x;
    if (i >= E2) return;
    int d = (i < E) ? ei[E + i] : (i - E);
    atomicAdd(&deg[d], 1);
}

__global__ __launch_bounds__(1024) void k_scan(const int* __restrict__ deg,
                                               int* __restrict__ row_ptr,
                                               int* __restrict__ cursor,
                                               int N, int E2) {
    __shared__ int sums[1024];
    int tid = threadIdx.x;
    int chunk = (N + 1023) / 1024;
    int st = tid * chunk;
    int en = min(N, st + chunk);
    int s = 0;
    for (int i = st; i < en; ++i) s += deg[i];
    sums[tid] = s;
    __syncthreads();
    for (int off = 1; off < 1024; off <<= 1) {
        int v = 0;
        if (tid >= off) v = sums[tid - off];
        __syncthreads();
        sums[tid] += v;
        __syncthreads();
    }
    int run = sums[tid] - s;  // exclusive prefix of this chunk
    for (int i = st; i < en; ++i) {
        row_ptr[i] = run;
        cursor[i] = run;
        run += deg[i];
    }
    if (tid == 0) row_ptr[N] = E2;
}

__global__ void k_fill(const int* __restrict__ ei, int* __restrict__ cursor,
                       int* __restrict__ edge_src, int N, int E, int E2) {
    int i = blockIdx.x * 256 + threadIdx.x;
    if (i >= E2) return;
    int s_, d_;
    if (i < E) { s_ = ei[i]; d_ = ei[E + i]; }
    else       { s_ = d_ = i - E; }
    int pos = atomicAdd(&cursor[d_], 1);
    edge_src[pos] = s_;
}

// ---------------- fp32 tiled GEMM: C[M,NC] = A[M,K] @ W[NC,K]^T (+bias)(+relu)
constexpr int BM = 64, BN = 64, BK = 64, PAD = 68;

template <int K, bool RELU>
__global__ __launch_bounds__(256) void k_gemm(const float* __restrict__ A,
                                              const float* __restrict__ W,
                                              const float* __restrict__ bias,
                                              float* __restrict__ C,
                                              int M, int NC) {
    __shared__ float As[BK][PAD];
    __shared__ float Bs[BK][PAD];
    int tid = threadIdx.x;
    int bm = blockIdx.x * BM;
    int bn = blockIdx.y * BN;
    int m0 = 4 * (tid & 15);
    int n0 = 4 * (tid >> 4);
    float acc[4][4] = {};

    for (int k0 = 0; k0 < K; k0 += BK) {
#pragma unroll
        for (int it = 0; it < 4; ++it) {
            int lin = it * 256 + tid;     // 0..1023
            int m = lin >> 4;             // 0..63
            int kq = lin & 15;            // 0..15 (x4 floats)
            float4 v = make_float4(0.f, 0.f, 0.f, 0.f);
            int row = bm + m;
            if (row < M)
                v = *reinterpret_cast<const float4*>(A + (size_t)row * K + k0 + kq * 4);
            As[kq * 4 + 0][m] = v.x; As[kq * 4 + 1][m] = v.y;
            As[kq * 4 + 2][m] = v.z; As[kq * 4 + 3][m] = v.w;
            float4 w = *reinterpret_cast<const float4*>(W + (size_t)(bn + m) * K + k0 + kq * 4);
            Bs[kq * 4 + 0][m] = w.x; Bs[kq * 4 + 1][m] = w.y;
            Bs[kq * 4 + 2][m] = w.z; Bs[kq * 4 + 3][m] = w.w;
        }
        __syncthreads();
#pragma unroll
        for (int k = 0; k < BK; ++k) {
            float4 a4 = *reinterpret_cast<const float4*>(&As[k][m0]);
            float4 b4 = *reinterpret_cast<const float4*>(&Bs[k][n0]);
            float av[4] = {a4.x, a4.y, a4.z, a4.w};
            float bv[4] = {b4.x, b4.y, b4.z, b4.w};
#pragma unroll
            for (int i = 0; i < 4; ++i)
#pragma unroll
                for (int j = 0; j < 4; ++j) acc[i][j] += av[i] * bv[j];
        }
        __syncthreads();
    }

    float bv[4] = {0.f, 0.f, 0.f, 0.f};
    if (bias) {
        bv[0] = bias[bn + n0 + 0]; bv[1] = bias[bn + n0 + 1];
        bv[2] = bias[bn + n0 + 2]; bv[3] = bias[bn + n0 + 3];
    }
#pragma unroll
    for (int i = 0; i < 4; ++i) {
        int row = bm + m0 + i;
        if (row < M) {
            float4 o;
            o.x = acc[i][0] + bv[0]; o.y = acc[i][1] + bv[1];
            o.z = acc[i][2] + bv[2]; o.w = acc[i][3] + bv[3];
            if (RELU) {
                o.x = fmaxf(o.x, 0.f); o.y = fmaxf(o.y, 0.f);
                o.z = fmaxf(o.z, 0.f); o.w = fmaxf(o.w, 0.f);
            }
            *reinterpret_cast<float4*>(C + (size_t)row * NC + bn + n0) = o;
        }
    }
}

// ---------------- per-(node,head) attention scores ----------------
template <int H>
__global__ __launch_bounds__(256) void k_scores(const float* __restrict__ h,
                                                const float* __restrict__ a_s,
                                                const float* __restrict__ a_d,
                                                float* __restrict__ sS,
                                                float* __restrict__ sD, int N) {
    int wid = threadIdx.x >> 6;
    int lane = threadIdx.x & 63;
    int gw = blockIdx.x * 4 + wid;
    if (gw >= N * H) return;
    int n = gw / H, hh = gw % H;
    float v = h[(size_t)n * (H * 64) + hh * 64 + lane];
    float ds = v * a_s[hh * 64 + lane];
    float dd = v * a_d[hh * 64 + lane];
#pragma unroll
    for (int off = 32; off; off >>= 1) {
        ds += __shfl_down(ds, off);
        dd += __shfl_down(dd, off);
    }
    if (lane == 0) { sS[n * H + hh] = ds; sD[n * H + hh] = dd; }
}

// ---------------- aggregation: online softmax + bias + (ELU) + LayerNorm ----
template <int H, bool ELU>
__global__ void k_agg(const float* __restrict__ h_in,
                      const float* __restrict__ sS, const float* __restrict__ sD,
                      const float* __restrict__ bias,
                      const float* __restrict__ ln_w, const float* __restrict__ ln_b,
                      const int* __restrict__ row_ptr, const int* __restrict__ edge_src,
                      float* __restrict__ out, int N, int ostride) {
    constexpr int D = H * 64;
    int n = blockIdx.x;
    int tid = threadIdx.x;           // 0..D-1
    int hh = tid >> 6;
    float sdn = sD[n * H + hh];
    int rs = row_ptr[n], re = row_ptr[n + 1];
    float m = -INFINITY, s = 0.f, acc = 0.f;
    for (int i = rs; i < re; ++i) {
        int src = edge_src[i];
        float e = sS[src * H + hh] + sdn;
        e = e > 0.f ? e : 0.2f * e;          // leaky_relu 0.2
        float mn = fmaxf(m, e);
        float sc = __expf(m - mn);
        float p = __expf(e - mn);
        s = s * sc + p;
        acc = acc * sc + p * h_in[(size_t)src * D + tid];
        m = mn;
    }
    float v = acc / (s + 1e-16f) + bias[tid];
    if (ELU) v = v > 0.f ? v : (__expf(v) - 1.f);

    // LayerNorm over D channels
    float sum = v, sq = v * v;
#pragma unroll
    for (int off = 1; off < 64; off <<= 1) {
        sum += __shfl_xor(sum, off);
        sq += __shfl_xor(sq, off);
    }
    if constexpr (H > 1) {
        __shared__ float red[2][H];
        if ((tid & 63) == 0) { red[0][hh] = sum; red[1][hh] = sq; }
        __syncthreads();
        sum = 0.f; sq = 0.f;
#pragma unroll
        for (int w = 0; w < H; ++w) { sum += red[0][w]; sq += red[1][w]; }
    }
    float mu = sum / D;
    float var = fmaxf(sq / D - mu * mu, 0.f);
    float y = (v - mu) * rsqrtf(var + 1e-5f) * ln_w[tid] + ln_b[tid];
    out[(size_t)n * ostride + tid] = y;
}

// ---------------- role embedding into concat buffer ----------------
__global__ void k_role(const int* __restrict__ role_ids,
                       const float* __restrict__ role_table,
                       float* __restrict__ cat, int N) {
    int i = blockIdx.x * 256 + threadIdx.x;
    int n = i >> 6, c = i & 63;
    if (n >= N) return;
    cat[(size_t)n * 128 + 64 + c] = role_table[role_ids[n] * 64 + c];
}

// ---------------------------------------------------------------------------
extern "C" void kernel_launch(void* const* d_in, const int* in_sizes, int n_in,
                              void* d_out, int out_size, void* d_ws, size_t ws_size,
                              hipStream_t stream) {
    const float* x        = (const float*)d_in[0];
    const int*   ei       = (const int*)d_in[1];
    const int*   role_ids = (const int*)d_in[2];
    const float* W1  = (const float*)d_in[3];
    const float* a1s = (const float*)d_in[4];
    const float* a1d = (const float*)d_in[5];
    const float* b1  = (const float*)d_in[6];
    const float* W2  = (const float*)d_in[7];
    const float* a2s = (const float*)d_in[8];
    const float* a2d = (const float*)d_in[9];
    const float* b2  = (const float*)d_in[10];
    const float* W3  = (const float*)d_in[11];
    const float* a3s = (const float*)d_in[12];
    const float* a3d = (const float*)d_in[13];
    const float* b3  = (const float*)d_in[14];
    const float* ln1w = (const float*)d_in[15];
    const float* ln1b = (const float*)d_in[16];
    const float* ln2w = (const float*)d_in[17];
    const float* ln2b = (const float*)d_in[18];
    const float* ln3w = (const float*)d_in[19];
    const float* ln3b = (const float*)d_in[20];
    const float* role_table = (const float*)d_in[21];
    const float* p1w = (const float*)d_in[22];
    const float* p1b = (const float*)d_in[23];
    const float* p2w = (const float*)d_in[24];
    const float* p2b = (const float*)d_in[25];

    const int N = in_sizes[0] / 64;
    const int E = in_sizes[1] / 2;
    const int E2 = E + N;

    // workspace carve
    char* p = (char*)d_ws;
    auto carve = [&](size_t bytes) -> char* {
        char* r = p;
        p += (bytes + 255) & ~(size_t)255;
        return r;
    };
    int* deg      = (int*)carve((size_t)N * 4);
    int* row_ptr  = (int*)carve((size_t)(N + 1) * 4);
    int* cursor   = (int*)carve((size_t)N * 4);
    int* edge_src = (int*)carve((size_t)E2 * 4);
    float* sS     = (float*)carve((size_t)N * 4 * 4);
    float* sD     = (float*)carve((size_t)N * 4 * 4);
    float* hbuf0  = (float*)carve((size_t)N * 256 * 4);
    float* hbuf1  = (float*)carve((size_t)N * 256 * 4);
    float* cat    = hbuf1;   // reused after gemm3 consumes hbuf1
    float* z1     = hbuf0;   // reused after agg3 consumes hbuf0

    // ---- CSR build ----
    hipMemsetAsync(deg, 0, (size_t)N * 4, stream);
    int eb = (E2 + 255) / 256;
    k_count<<<eb, 256, 0, stream>>>(ei, deg, N, E, E2);
    k_scan<<<1, 1024, 0, stream>>>(deg, row_ptr, cursor, N, E2);
    k_fill<<<eb, 256, 0, stream>>>(ei, cursor, edge_src, N, E, E2);

    int mb = (N + BM - 1) / BM;

    // ---- layer 1: 64 -> 4x64 ----
    dim3 g1(mb, 4);
    k_gemm<64, false><<<g1, 256, 0, stream>>>(x, W1, nullptr, hbuf0, N, 256);
    k_scores<4><<<(N * 4 + 3) / 4, 256, 0, stream>>>(hbuf0, a1s, a1d, sS, sD, N);
    k_agg<4, true><<<N, 256, 0, stream>>>(hbuf0, sS, sD, b1, ln1w, ln1b,
                                          row_ptr, edge_src, hbuf1, N, 256);

    // ---- layer 2: 256 -> 4x64 ----
    dim3 g2(mb, 4);
    k_gemm<256, false><<<g2, 256, 0, stream>>>(hbuf1, W2, nullptr, hbuf0, N, 256);
    k_scores<4><<<(N * 4 + 3) / 4, 256, 0, stream>>>(hbuf0, a2s, a2d, sS, sD, N);
    k_agg<4, true><<<N, 256, 0, stream>>>(hbuf0, sS, sD, b2, ln2w, ln2b,
                                          row_ptr, edge_src, hbuf1, N, 256);

    // ---- layer 3: 256 -> 64 (1 head, no concat) ----
    dim3 g3(mb, 1);
    k_gemm<256, false><<<g3, 256, 0, stream>>>(hbuf1, W3, nullptr, hbuf0, N, 64);
    k_scores<1><<<(N + 3) / 4, 256, 0, stream>>>(hbuf0, a3s, a3d, sS, sD, N);
    k_role<<<(N * 64 + 255) / 256, 256, 0, stream>>>(role_ids, role_table, cat, N);
    k_agg<1, false><<<N, 64, 0, stream>>>(hbuf0, sS, sD, b3, ln3w, ln3b,
                                          row_ptr, edge_src, cat, N, 128);

    // ---- MLP: cat[N,128] -> relu -> [N,64] -> out ----
    dim3 g4(mb, 1);
    k_gemm<128, true><<<g4, 256, 0, stream>>>(cat, p1w, p1b, z1, N, 64);
    k_gemm<64, false><<<g4, 256, 0, stream>>>(z1, p2w, p2b, (float*)d_out, N, 64);
}

// Round 2
// 737.760 us; speedup vs baseline: 1.4505x; 1.4505x over previous
//
#include <hip/hip_runtime.h>
#include <math.h>

// ---------------------------------------------------------------------------
// TopologyAwareGATEncoder: 3x GATConv(+ELU+LN) -> concat role emb -> 2-layer MLP
// N=50000, E=400000 (+N self loops), IN=64, HID=64, HEADS=4
// ---------------------------------------------------------------------------

// ---------------- CSR build ----------------
__global__ void k_count(const int* __restrict__ ei, int* __restrict__ deg,
                        int N, int E, int E2) {
    int i = blockIdx.x * 256 + threadIdx.x;
    if (i >= E2) return;
    int d = (i < E) ? ei[E + i] : (i - E);
    atomicAdd(&deg[d], 1);
}

__global__ __launch_bounds__(1024) void k_scan(const int* __restrict__ deg,
                                               int* __restrict__ row_ptr,
                                               int* __restrict__ cursor,
                                               int N, int E2) {
    __shared__ int sums[1024];
    int tid = threadIdx.x;
    int chunk = (N + 1023) / 1024;
    int st = tid * chunk;
    int en = min(N, st + chunk);
    int s = 0;
    for (int i = st; i < en; ++i) s += deg[i];
    sums[tid] = s;
    __syncthreads();
    for (int off = 1; off < 1024; off <<= 1) {
        int v = 0;
        if (tid >= off) v = sums[tid - off];
        __syncthreads();
        sums[tid] += v;
        __syncthreads();
    }
    int run = sums[tid] - s;  // exclusive prefix of this chunk
    for (int i = st; i < en; ++i) {
        row_ptr[i] = run;
        cursor[i] = run;
        run += deg[i];
    }
    if (tid == 0) row_ptr[N] = E2;
}

__global__ void k_fill(const int* __restrict__ ei, int* __restrict__ cursor,
                       int* __restrict__ edge_src, int N, int E, int E2) {
    int i = blockIdx.x * 256 + threadIdx.x;
    if (i >= E2) return;
    int s_, d_;
    if (i < E) { s_ = ei[i]; d_ = ei[E + i]; }
    else       { s_ = d_ = i - E; }
    int pos = atomicAdd(&cursor[d_], 1);
    edge_src[pos] = s_;
}

// ---------------- fp32 tiled GEMM v2: C[M,NC] = A[M,K] @ W[NC,K]^T ----------
// 128x128 (or 128x64) tile, BK=16, 256 threads, 8x8 micro-tile split into
// 4+4 quads so LDS reads are float4 broadcast (A) / 2-way (B): conflict-free.
constexpr int BM2 = 128, BK2 = 16;

template <int K, int BN, bool RELU>
__global__ __launch_bounds__(256) void k_gemm2(const float* __restrict__ A,
                                               const float* __restrict__ W,
                                               const float* __restrict__ bias,
                                               float* __restrict__ C,
                                               int M, int NC) {
    constexpr int CQ = BN / 64;                 // 2 for BN=128, 1 for BN=64
    __shared__ float As[BK2][BM2 + 4];
    __shared__ float Bs[BK2][BN + 4];
    int tid = threadIdx.x;
    int tx = tid & 15, ty = tid >> 4;
    int bm = blockIdx.x * BM2;
    int bn = blockIdx.y * BN;
    float acc[8][CQ * 4] = {};

    for (int k0 = 0; k0 < K; k0 += BK2) {
        // stage A tile: 128 rows x 16 k = 512 float4 chunks, 2 per thread
#pragma unroll
        for (int it = 0; it < 2; ++it) {
            int c = it * 256 + tid;
            int r = c >> 2, kq = c & 3;
            float4 v = make_float4(0.f, 0.f, 0.f, 0.f);
            if (bm + r < M)
                v = *reinterpret_cast<const float4*>(A + (size_t)(bm + r) * K + k0 + kq * 4);
            As[kq * 4 + 0][r] = v.x; As[kq * 4 + 1][r] = v.y;
            As[kq * 4 + 2][r] = v.z; As[kq * 4 + 3][r] = v.w;
        }
        // stage B tile: BN rows x 16 k
#pragma unroll
        for (int it = 0; it < CQ; ++it) {
            int c = it * 256 + tid;
            int r = c >> 2, kq = c & 3;
            float4 v = *reinterpret_cast<const float4*>(W + (size_t)(bn + r) * K + k0 + kq * 4);
            Bs[kq * 4 + 0][r] = v.x; Bs[kq * 4 + 1][r] = v.y;
            Bs[kq * 4 + 2][r] = v.z; Bs[kq * 4 + 3][r] = v.w;
        }
        __syncthreads();
#pragma unroll
        for (int kk = 0; kk < BK2; ++kk) {
            float4 a0 = *reinterpret_cast<const float4*>(&As[kk][ty * 4]);
            float4 a1 = *reinterpret_cast<const float4*>(&As[kk][ty * 4 + 64]);
            float av[8] = {a0.x, a0.y, a0.z, a0.w, a1.x, a1.y, a1.z, a1.w};
            float bv[CQ * 4];
            float4 b0 = *reinterpret_cast<const float4*>(&Bs[kk][tx * 4]);
            bv[0] = b0.x; bv[1] = b0.y; bv[2] = b0.z; bv[3] = b0.w;
            if constexpr (CQ == 2) {
                float4 b1 = *reinterpret_cast<const float4*>(&Bs[kk][tx * 4 + 64]);
                bv[4] = b1.x; bv[5] = b1.y; bv[6] = b1.z; bv[7] = b1.w;
            }
#pragma unroll
            for (int i = 0; i < 8; ++i)
#pragma unroll
                for (int j = 0; j < CQ * 4; ++j) acc[i][j] += av[i] * bv[j];
        }
        __syncthreads();
    }

    // epilogue
    float bb[CQ * 4];
#pragma unroll
    for (int q = 0; q < CQ; ++q) {
        float4 b4 = bias ? *reinterpret_cast<const float4*>(bias + bn + q * 64 + tx * 4)
                         : make_float4(0.f, 0.f, 0.f, 0.f);
        bb[q * 4 + 0] = b4.x; bb[q * 4 + 1] = b4.y;
        bb[q * 4 + 2] = b4.z; bb[q * 4 + 3] = b4.w;
    }
#pragma unroll
    for (int i = 0; i < 8; ++i) {
        int r = (i < 4) ? (ty * 4 + i) : (64 + ty * 4 + i - 4);
        int row = bm + r;
        if (row >= M) continue;
#pragma unroll
        for (int q = 0; q < CQ; ++q) {
            float4 o;
            o.x = acc[i][q * 4 + 0] + bb[q * 4 + 0];
            o.y = acc[i][q * 4 + 1] + bb[q * 4 + 1];
            o.z = acc[i][q * 4 + 2] + bb[q * 4 + 2];
            o.w = acc[i][q * 4 + 3] + bb[q * 4 + 3];
            if (RELU) {
                o.x = fmaxf(o.x, 0.f); o.y = fmaxf(o.y, 0.f);
                o.z = fmaxf(o.z, 0.f); o.w = fmaxf(o.w, 0.f);
            }
            *reinterpret_cast<float4*>(C + (size_t)row * NC + bn + q * 64 + tx * 4) = o;
        }
    }
}

// ---------------- per-(node,head) attention scores ----------------
template <int H>
__global__ __launch_bounds__(256) void k_scores(const float* __restrict__ h,
                                                const float* __restrict__ a_s,
                                                const float* __restrict__ a_d,
                                                float* __restrict__ sS,
                                                float* __restrict__ sD, int N) {
    int wid = threadIdx.x >> 6;
    int lane = threadIdx.x & 63;
    int gw = blockIdx.x * 4 + wid;
    if (gw >= N * H) return;
    int n = gw / H, hh = gw % H;
    float v = h[(size_t)n * (H * 64) + hh * 64 + lane];
    float ds = v * a_s[hh * 64 + lane];
    float dd = v * a_d[hh * 64 + lane];
#pragma unroll
    for (int off = 32; off; off >>= 1) {
        ds += __shfl_down(ds, off);
        dd += __shfl_down(dd, off);
    }
    if (lane == 0) { sS[n * H + hh] = ds; sD[n * H + hh] = dd; }
}

// ---------------- aggregation: online softmax + bias + (ELU) + LayerNorm ----
template <int H, bool ELU>
__global__ void k_agg(const float* __restrict__ h_in,
                      const float* __restrict__ sS, const float* __restrict__ sD,
                      const float* __restrict__ bias,
                      const float* __restrict__ ln_w, const float* __restrict__ ln_b,
                      const int* __restrict__ row_ptr, const int* __restrict__ edge_src,
                      float* __restrict__ out, int N, int ostride) {
    constexpr int D = H * 64;
    int n = blockIdx.x;
    int tid = threadIdx.x;           // 0..D-1
    int hh = tid >> 6;
    float sdn = sD[n * H + hh];
    int rs = row_ptr[n], re = row_ptr[n + 1];
    float m = -INFINITY, s = 0.f, acc = 0.f;
    for (int i = rs; i < re; ++i) {
        int src = edge_src[i];
        float e = sS[src * H + hh] + sdn;
        e = e > 0.f ? e : 0.2f * e;          // leaky_relu 0.2
        float mn = fmaxf(m, e);
        float sc = __expf(m - mn);
        float p = __expf(e - mn);
        s = s * sc + p;
        acc = acc * sc + p * h_in[(size_t)src * D + tid];
        m = mn;
    }
    float v = acc / (s + 1e-16f) + bias[tid];
    if (ELU) v = v > 0.f ? v : (__expf(v) - 1.f);

    // LayerNorm over D channels
    float sum = v, sq = v * v;
#pragma unroll
    for (int off = 1; off < 64; off <<= 1) {
        sum += __shfl_xor(sum, off);
        sq += __shfl_xor(sq, off);
    }
    if constexpr (H > 1) {
        __shared__ float red[2][H];
        if ((tid & 63) == 0) { red[0][hh] = sum; red[1][hh] = sq; }
        __syncthreads();
        sum = 0.f; sq = 0.f;
#pragma unroll
        for (int w = 0; w < H; ++w) { sum += red[0][w]; sq += red[1][w]; }
    }
    float mu = sum / D;
    float var = fmaxf(sq / D - mu * mu, 0.f);
    float y = (v - mu) * rsqrtf(var + 1e-5f) * ln_w[tid] + ln_b[tid];
    out[(size_t)n * ostride + tid] = y;
}

// ---------------- role embedding into concat buffer ----------------
__global__ void k_role(const int* __restrict__ role_ids,
                       const float* __restrict__ role_table,
                       float* __restrict__ cat, int N) {
    int i = blockIdx.x * 256 + threadIdx.x;
    int n = i >> 6, c = i & 63;
    if (n >= N) return;
    cat[(size_t)n * 128 + 64 + c] = role_table[role_ids[n] * 64 + c];
}

// ---------------------------------------------------------------------------
extern "C" void kernel_launch(void* const* d_in, const int* in_sizes, int n_in,
                              void* d_out, int out_size, void* d_ws, size_t ws_size,
                              hipStream_t stream) {
    const float* x        = (const float*)d_in[0];
    const int*   ei       = (const int*)d_in[1];
    const int*   role_ids = (const int*)d_in[2];
    const float* W1  = (const float*)d_in[3];
    const float* a1s = (const float*)d_in[4];
    const float* a1d = (const float*)d_in[5];
    const float* b1  = (const float*)d_in[6];
    const float* W2  = (const float*)d_in[7];
    const float* a2s = (const float*)d_in[8];
    const float* a2d = (const float*)d_in[9];
    const float* b2  = (const float*)d_in[10];
    const float* W3  = (const float*)d_in[11];
    const float* a3s = (const float*)d_in[12];
    const float* a3d = (const float*)d_in[13];
    const float* b3  = (const float*)d_in[14];
    const float* ln1w = (const float*)d_in[15];
    const float* ln1b = (const float*)d_in[16];
    const float* ln2w = (const float*)d_in[17];
    const float* ln2b = (const float*)d_in[18];
    const float* ln3w = (const float*)d_in[19];
    const float* ln3b = (const float*)d_in[20];
    const float* role_table = (const float*)d_in[21];
    const float* p1w = (const float*)d_in[22];
    const float* p1b = (const float*)d_in[23];
    const float* p2w = (const float*)d_in[24];
    const float* p2b = (const float*)d_in[25];

    const int N = in_sizes[0] / 64;
    const int E = in_sizes[1] / 2;
    const int E2 = E + N;

    // workspace carve
    char* p = (char*)d_ws;
    auto carve = [&](size_t bytes) -> char* {
        char* r = p;
        p += (bytes + 255) & ~(size_t)255;
        return r;
    };
    int* deg      = (int*)carve((size_t)N * 4);
    int* row_ptr  = (int*)carve((size_t)(N + 1) * 4);
    int* cursor   = (int*)carve((size_t)N * 4);
    int* edge_src = (int*)carve((size_t)E2 * 4);
    float* sS     = (float*)carve((size_t)N * 4 * 4);
    float* sD     = (float*)carve((size_t)N * 4 * 4);
    float* hbuf0  = (float*)carve((size_t)N * 256 * 4);
    float* hbuf1  = (float*)carve((size_t)N * 256 * 4);
    float* cat    = hbuf1;   // reused after gemm3 consumes hbuf1
    float* z1     = hbuf0;   // reused after agg3 consumes hbuf0

    // ---- CSR build ----
    hipMemsetAsync(deg, 0, (size_t)N * 4, stream);
    int eb = (E2 + 255) / 256;
    k_count<<<eb, 256, 0, stream>>>(ei, deg, N, E, E2);
    k_scan<<<1, 1024, 0, stream>>>(deg, row_ptr, cursor, N, E2);
    k_fill<<<eb, 256, 0, stream>>>(ei, cursor, edge_src, N, E, E2);

    int mb = (N + BM2 - 1) / BM2;

    // ---- layer 1: 64 -> 4x64 ----
    k_gemm2<64, 128, false><<<dim3(mb, 2), 256, 0, stream>>>(x, W1, nullptr, hbuf0, N, 256);
    k_scores<4><<<(N * 4 + 3) / 4, 256, 0, stream>>>(hbuf0, a1s, a1d, sS, sD, N);
    k_agg<4, true><<<N, 256, 0, stream>>>(hbuf0, sS, sD, b1, ln1w, ln1b,
                                          row_ptr, edge_src, hbuf1, N, 256);

    // ---- layer 2: 256 -> 4x64 ----
    k_gemm2<256, 128, false><<<dim3(mb, 2), 256, 0, stream>>>(hbuf1, W2, nullptr, hbuf0, N, 256);
    k_scores<4><<<(N * 4 + 3) / 4, 256, 0, stream>>>(hbuf0, a2s, a2d, sS, sD, N);
    k_agg<4, true><<<N, 256, 0, stream>>>(hbuf0, sS, sD, b2, ln2w, ln2b,
                                          row_ptr, edge_src, hbuf1, N, 256);

    // ---- layer 3: 256 -> 64 (1 head, no concat) ----
    k_gemm2<256, 64, false><<<dim3(mb, 1), 256, 0, stream>>>(hbuf1, W3, nullptr, hbuf0, N, 64);
    k_scores<1><<<(N + 3) / 4, 256, 0, stream>>>(hbuf0, a3s, a3d, sS, sD, N);
    k_role<<<(N * 64 + 255) / 256, 256, 0, stream>>>(role_ids, role_table, cat, N);
    k_agg<1, false><<<N, 64, 0, stream>>>(hbuf0, sS, sD, b3, ln3w, ln3b,
                                          row_ptr, edge_src, cat, N, 128);

    // ---- MLP: cat[N,128] -> relu -> [N,64] -> out ----
    k_gemm2<128, 64, true><<<dim3(mb, 1), 256, 0, stream>>>(cat, p1w, p1b, z1, N, 64);
    k_gemm2<64, 64, false><<<dim3(mb, 1), 256, 0, stream>>>(z1, p2w, p2b, (float*)d_out, N, 64);
}

// Round 3
// 715.573 us; speedup vs baseline: 1.4955x; 1.0310x over previous
//
#include <hip/hip_runtime.h>
#include <math.h>

// ---------------------------------------------------------------------------
// TopologyAwareGATEncoder: 3x GATConv(+ELU+LN) -> concat role emb -> 2-layer MLP
// N=50000, E=400000 (+N self loops), IN=64, HID=64, HEADS=4
// ---------------------------------------------------------------------------

__device__ __forceinline__ unsigned short f2bf(float f) {
    unsigned int u = __builtin_bit_cast(unsigned int, f);
    u += 0x7fffu + ((u >> 16) & 1u);     // RN-even
    return (unsigned short)(u >> 16);
}
__device__ __forceinline__ float bf2f(unsigned short b) {
    unsigned int u = ((unsigned int)b) << 16;
    return __builtin_bit_cast(float, u);
}

// ---------------- CSR build ----------------
__global__ void k_count(const int* __restrict__ ei, int* __restrict__ deg,
                        int N, int E, int E2) {
    int i = blockIdx.x * 256 + threadIdx.x;
    if (i >= E2) return;
    int d = (i < E) ? ei[E + i] : (i - E);
    atomicAdd(&deg[d], 1);
}

__global__ __launch_bounds__(1024) void k_scan(const int* __restrict__ deg,
                                               int* __restrict__ row_ptr,
                                               int* __restrict__ cursor,
                                               int N, int E2) {
    __shared__ int sums[1024];
    int tid = threadIdx.x;
    int chunk = (N + 1023) / 1024;
    int st = tid * chunk;
    int en = min(N, st + chunk);
    int s = 0;
    for (int i = st; i < en; ++i) s += deg[i];
    sums[tid] = s;
    __syncthreads();
    for (int off = 1; off < 1024; off <<= 1) {
        int v = 0;
        if (tid >= off) v = sums[tid - off];
        __syncthreads();
        sums[tid] += v;
        __syncthreads();
    }
    int run = sums[tid] - s;  // exclusive prefix of this chunk
    for (int i = st; i < en; ++i) {
        row_ptr[i] = run;
        cursor[i] = run;
        run += deg[i];
    }
    if (tid == 0) row_ptr[N] = E2;
}

__global__ void k_fill(const int* __restrict__ ei, int* __restrict__ cursor,
                       int* __restrict__ edge_src, int N, int E, int E2) {
    int i = blockIdx.x * 256 + threadIdx.x;
    if (i >= E2) return;
    int s_, d_;
    if (i < E) { s_ = ei[i]; d_ = ei[E + i]; }
    else       { s_ = d_ = i - E; }
    int pos = atomicAdd(&cursor[d_], 1);
    edge_src[pos] = s_;
}

// ---------------- fp32 tiled GEMM: C[M,NC] = A[M,K] @ W[NC,K]^T -------------
// 128x{128,64} tile, BK=16, 256 threads, 8x(4*CQ) micro-tile, quad-split LDS
// reads (A broadcast, B 2-way): conflict-free. Optional bf16 C store.
constexpr int BM2 = 128, BK2 = 16;

template <int K, int BN, bool RELU, bool BF16OUT>
__global__ __launch_bounds__(256) void k_gemm2(const float* __restrict__ A,
                                               const float* __restrict__ W,
                                               const float* __restrict__ bias,
                                               void* __restrict__ Cv,
                                               int M, int NC) {
    constexpr int CQ = BN / 64;                 // 2 for BN=128, 1 for BN=64
    __shared__ float As[BK2][BM2 + 4];
    __shared__ float Bs[BK2][BN + 4];
    int tid = threadIdx.x;
    int tx = tid & 15, ty = tid >> 4;
    int bm = blockIdx.x * BM2;
    int bn = blockIdx.y * BN;
    float acc[8][CQ * 4] = {};

    for (int k0 = 0; k0 < K; k0 += BK2) {
#pragma unroll
        for (int it = 0; it < 2; ++it) {
            int c = it * 256 + tid;
            int r = c >> 2, kq = c & 3;
            float4 v = make_float4(0.f, 0.f, 0.f, 0.f);
            if (bm + r < M)
                v = *reinterpret_cast<const float4*>(A + (size_t)(bm + r) * K + k0 + kq * 4);
            As[kq * 4 + 0][r] = v.x; As[kq * 4 + 1][r] = v.y;
            As[kq * 4 + 2][r] = v.z; As[kq * 4 + 3][r] = v.w;
        }
#pragma unroll
        for (int it = 0; it < CQ; ++it) {
            int c = it * 256 + tid;
            int r = c >> 2, kq = c & 3;
            float4 v = *reinterpret_cast<const float4*>(W + (size_t)(bn + r) * K + k0 + kq * 4);
            Bs[kq * 4 + 0][r] = v.x; Bs[kq * 4 + 1][r] = v.y;
            Bs[kq * 4 + 2][r] = v.z; Bs[kq * 4 + 3][r] = v.w;
        }
        __syncthreads();
#pragma unroll
        for (int kk = 0; kk < BK2; ++kk) {
            float4 a0 = *reinterpret_cast<const float4*>(&As[kk][ty * 4]);
            float4 a1 = *reinterpret_cast<const float4*>(&As[kk][ty * 4 + 64]);
            float av[8] = {a0.x, a0.y, a0.z, a0.w, a1.x, a1.y, a1.z, a1.w};
            float bv[CQ * 4];
            float4 b0 = *reinterpret_cast<const float4*>(&Bs[kk][tx * 4]);
            bv[0] = b0.x; bv[1] = b0.y; bv[2] = b0.z; bv[3] = b0.w;
            if constexpr (CQ == 2) {
                float4 b1 = *reinterpret_cast<const float4*>(&Bs[kk][tx * 4 + 64]);
                bv[4] = b1.x; bv[5] = b1.y; bv[6] = b1.z; bv[7] = b1.w;
            }
#pragma unroll
            for (int i = 0; i < 8; ++i)
#pragma unroll
                for (int j = 0; j < CQ * 4; ++j) acc[i][j] += av[i] * bv[j];
        }
        __syncthreads();
    }

    float bb[CQ * 4];
#pragma unroll
    for (int q = 0; q < CQ; ++q) {
        float4 b4 = bias ? *reinterpret_cast<const float4*>(bias + bn + q * 64 + tx * 4)
                         : make_float4(0.f, 0.f, 0.f, 0.f);
        bb[q * 4 + 0] = b4.x; bb[q * 4 + 1] = b4.y;
        bb[q * 4 + 2] = b4.z; bb[q * 4 + 3] = b4.w;
    }
#pragma unroll
    for (int i = 0; i < 8; ++i) {
        int r = (i < 4) ? (ty * 4 + i) : (64 + ty * 4 + i - 4);
        int row = bm + r;
        if (row >= M) continue;
#pragma unroll
        for (int q = 0; q < CQ; ++q) {
            float o0 = acc[i][q * 4 + 0] + bb[q * 4 + 0];
            float o1 = acc[i][q * 4 + 1] + bb[q * 4 + 1];
            float o2 = acc[i][q * 4 + 2] + bb[q * 4 + 2];
            float o3 = acc[i][q * 4 + 3] + bb[q * 4 + 3];
            if (RELU) {
                o0 = fmaxf(o0, 0.f); o1 = fmaxf(o1, 0.f);
                o2 = fmaxf(o2, 0.f); o3 = fmaxf(o3, 0.f);
            }
            if constexpr (BF16OUT) {
                ushort4 u;
                u.x = f2bf(o0); u.y = f2bf(o1); u.z = f2bf(o2); u.w = f2bf(o3);
                *reinterpret_cast<ushort4*>((unsigned short*)Cv +
                    (size_t)row * NC + bn + q * 64 + tx * 4) = u;
            } else {
                float4 o = make_float4(o0, o1, o2, o3);
                *reinterpret_cast<float4*>((float*)Cv +
                    (size_t)row * NC + bn + q * 64 + tx * 4) = o;
            }
        }
    }
}

// ---------------- per-(node,head) attention scores (bf16 h) ----------------
template <int H>
__global__ __launch_bounds__(256) void k_scores(const unsigned short* __restrict__ h,
                                                const float* __restrict__ a_s,
                                                const float* __restrict__ a_d,
                                                float* __restrict__ sS,
                                                float* __restrict__ sD, int N) {
    int wid = threadIdx.x >> 6;
    int lane = threadIdx.x & 63;
    int gw = blockIdx.x * 4 + wid;
    if (gw >= N * H) return;
    int n = gw / H, hh = gw % H;
    float v = bf2f(h[(size_t)n * (H * 64) + hh * 64 + lane]);
    float ds = v * a_s[hh * 64 + lane];
    float dd = v * a_d[hh * 64 + lane];
#pragma unroll
    for (int off = 32; off; off >>= 1) {
        ds += __shfl_down(ds, off);
        dd += __shfl_down(dd, off);
    }
    if (lane == 0) { sS[n * H + hh] = ds; sD[n * H + hh] = dd; }
}

// ---------------- per-(node,head) softmax weights: p=exp(e-m), sden=sum ----
template <int H>
__global__ void k_alpha(const float* __restrict__ sS, const float* __restrict__ sD,
                        const int* __restrict__ row_ptr, const int* __restrict__ edge_src,
                        float* __restrict__ alpha, float* __restrict__ sden, int NH) {
    int gid = blockIdx.x * 256 + threadIdx.x;
    if (gid >= NH) return;
    int n = gid / H;
    int h = gid - n * H;
    float sdn = sD[gid];
    int rs = row_ptr[n], re = row_ptr[n + 1];
    float m = -1e30f;
    for (int i = rs; i < re; ++i) {
        float e = sS[edge_src[i] * H + h] + sdn;
        e = e > 0.f ? e : 0.2f * e;          // leaky_relu 0.2
        alpha[i * H + h] = e;
        m = fmaxf(m, e);
    }
    float s = 0.f;
    for (int i = rs; i < re; ++i) {
        float p = __expf(alpha[i * H + h] - m);
        alpha[i * H + h] = p;
        s += p;
    }
    sden[gid] = s;
}

// ---------------- aggregation (bf16 gather) + bias + (ELU) + LayerNorm -----
// D channels per node, 2 channels/thread -> TPN=D/2 threads per node,
// NPB=256/TPN nodes per block.
template <int D, bool ELU>
__global__ __launch_bounds__(256) void k_aggb(
        const unsigned short* __restrict__ hbf,
        const float* __restrict__ alpha, const float* __restrict__ sden,
        const float* __restrict__ bias,
        const float* __restrict__ ln_w, const float* __restrict__ ln_b,
        const int* __restrict__ row_ptr, const int* __restrict__ edge_src,
        float* __restrict__ out, int N, int ostride) {
    constexpr int H = D / 64;
    constexpr int TPN = D / 2;
    constexpr int NPB = 256 / TPN;
    int tid = threadIdx.x;
    int n = blockIdx.x * NPB + tid / TPN;
    int t = tid % TPN;
    int c0 = 2 * t;
    int hh = c0 >> 6;
    if (n >= N) return;

    int rs = row_ptr[n], re = row_ptr[n + 1];
    float a0 = 0.f, a1 = 0.f;
    for (int i = rs; i < re; ++i) {
        int src = edge_src[i];
        float p = alpha[i * H + hh];
        unsigned int u = *reinterpret_cast<const unsigned int*>(
            hbf + (size_t)src * D + c0);
        a0 += p * bf2f((unsigned short)(u & 0xffffu));
        a1 += p * bf2f((unsigned short)(u >> 16));
    }
    float inv = 1.f / (sden[n * H + hh] + 1e-16f);
    float v0 = a0 * inv + bias[c0];
    float v1 = a1 * inv + bias[c0 + 1];
    if (ELU) {
        v0 = v0 > 0.f ? v0 : (__expf(v0) - 1.f);
        v1 = v1 > 0.f ? v1 : (__expf(v1) - 1.f);
    }

    // LayerNorm over D channels
    float sum = v0 + v1, sq = v0 * v0 + v1 * v1;
    if constexpr (TPN == 32) {
        // node spans half a wave: butterfly within 32 lanes
#pragma unroll
        for (int off = 1; off < 32; off <<= 1) {
            sum += __shfl_xor(sum, off);
            sq += __shfl_xor(sq, off);
        }
    } else {
        // TPN=128: node spans 2 waves; wave-reduce then LDS combine
#pragma unroll
        for (int off = 1; off < 64; off <<= 1) {
            sum += __shfl_xor(sum, off);
            sq += __shfl_xor(sq, off);
        }
        __shared__ float red[2][4];
        int w = tid >> 6;
        if ((tid & 63) == 0) { red[0][w] = sum; red[1][w] = sq; }
        __syncthreads();
        int wb = (tid >> 7) * 2;
        sum = red[0][wb] + red[0][wb + 1];
        sq = red[1][wb] + red[1][wb + 1];
    }
    float mu = sum / D;
    float var = fmaxf(sq / D - mu * mu, 0.f);
    float rstd = rsqrtf(var + 1e-5f);
    float y0 = (v0 - mu) * rstd * ln_w[c0] + ln_b[c0];
    float y1 = (v1 - mu) * rstd * ln_w[c0 + 1] + ln_b[c0 + 1];
    *reinterpret_cast<float2*>(out + (size_t)n * ostride + c0) = make_float2(y0, y1);
}

// ---------------- role embedding into concat buffer ----------------
__global__ void k_role(const int* __restrict__ role_ids,
                       const float* __restrict__ role_table,
                       float* __restrict__ cat, int N) {
    int i = blockIdx.x * 256 + threadIdx.x;
    int n = i >> 6, c = i & 63;
    if (n >= N) return;
    cat[(size_t)n * 128 + 64 + c] = role_table[role_ids[n] * 64 + c];
}

// ---------------------------------------------------------------------------
extern "C" void kernel_launch(void* const* d_in, const int* in_sizes, int n_in,
                              void* d_out, int out_size, void* d_ws, size_t ws_size,
                              hipStream_t stream) {
    const float* x        = (const float*)d_in[0];
    const int*   ei       = (const int*)d_in[1];
    const int*   role_ids = (const int*)d_in[2];
    const float* W1  = (const float*)d_in[3];
    const float* a1s = (const float*)d_in[4];
    const float* a1d = (const float*)d_in[5];
    const float* b1  = (const float*)d_in[6];
    const float* W2  = (const float*)d_in[7];
    const float* a2s = (const float*)d_in[8];
    const float* a2d = (const float*)d_in[9];
    const float* b2  = (const float*)d_in[10];
    const float* W3  = (const float*)d_in[11];
    const float* a3s = (const float*)d_in[12];
    const float* a3d = (const float*)d_in[13];
    const float* b3  = (const float*)d_in[14];
    const float* ln1w = (const float*)d_in[15];
    const float* ln1b = (const float*)d_in[16];
    const float* ln2w = (const float*)d_in[17];
    const float* ln2b = (const float*)d_in[18];
    const float* ln3w = (const float*)d_in[19];
    const float* ln3b = (const float*)d_in[20];
    const float* role_table = (const float*)d_in[21];
    const float* p1w = (const float*)d_in[22];
    const float* p1b = (const float*)d_in[23];
    const float* p2w = (const float*)d_in[24];
    const float* p2b = (const float*)d_in[25];

    const int N = in_sizes[0] / 64;
    const int E = in_sizes[1] / 2;
    const int E2 = E + N;

    // workspace carve
    char* p = (char*)d_ws;
    auto carve = [&](size_t bytes) -> char* {
        char* r = p;
        p += (bytes + 255) & ~(size_t)255;
        return r;
    };
    int* deg      = (int*)carve((size_t)N * 4);
    int* row_ptr  = (int*)carve((size_t)(N + 1) * 4);
    int* cursor   = (int*)carve((size_t)N * 4);
    int* edge_src = (int*)carve((size_t)E2 * 4);
    float* sS     = (float*)carve((size_t)N * 4 * 4);
    float* sD     = (float*)carve((size_t)N * 4 * 4);
    float* alpha  = (float*)carve((size_t)E2 * 4 * 4);
    float* sden   = (float*)carve((size_t)N * 4 * 4);
    unsigned short* hbf = (unsigned short*)carve((size_t)N * 256 * 2);
    float* hln    = (float*)carve((size_t)N * 256 * 4);
    float* cat    = (float*)carve((size_t)N * 128 * 4);
    float* z1     = hln;   // reused after MLP gemm1's input (cat) is separate

    // ---- CSR build ----
    hipMemsetAsync(deg, 0, (size_t)N * 4, stream);
    int eb = (E2 + 255) / 256;
    k_count<<<eb, 256, 0, stream>>>(ei, deg, N, E, E2);
    k_scan<<<1, 1024, 0, stream>>>(deg, row_ptr, cursor, N, E2);
    k_fill<<<eb, 256, 0, stream>>>(ei, cursor, edge_src, N, E, E2);

    int mb = (N + BM2 - 1) / BM2;

    // ---- layer 1: 64 -> 4x64 ----
    k_gemm2<64, 128, false, true><<<dim3(mb, 2), 256, 0, stream>>>(x, W1, nullptr, hbf, N, 256);
    k_scores<4><<<(N * 4 + 3) / 4, 256, 0, stream>>>(hbf, a1s, a1d, sS, sD, N);
    k_alpha<4><<<(N * 4 + 255) / 256, 256, 0, stream>>>(sS, sD, row_ptr, edge_src, alpha, sden, N * 4);
    k_aggb<256, true><<<(N + 1) / 2, 256, 0, stream>>>(hbf, alpha, sden, b1, ln1w, ln1b,
                                                       row_ptr, edge_src, hln, N, 256);

    // ---- layer 2: 256 -> 4x64 ----
    k_gemm2<256, 128, false, true><<<dim3(mb, 2), 256, 0, stream>>>(hln, W2, nullptr, hbf, N, 256);
    k_scores<4><<<(N * 4 + 3) / 4, 256, 0, stream>>>(hbf, a2s, a2d, sS, sD, N);
    k_alpha<4><<<(N * 4 + 255) / 256, 256, 0, stream>>>(sS, sD, row_ptr, edge_src, alpha, sden, N * 4);
    k_aggb<256, true><<<(N + 1) / 2, 256, 0, stream>>>(hbf, alpha, sden, b2, ln2w, ln2b,
                                                       row_ptr, edge_src, hln, N, 256);

    // ---- layer 3: 256 -> 64 (1 head, no concat) ----
    k_gemm2<256, 64, false, true><<<dim3(mb, 1), 256, 0, stream>>>(hln, W3, nullptr, hbf, N, 64);
    k_scores<1><<<(N + 3) / 4, 256, 0, stream>>>(hbf, a3s, a3d, sS, sD, N);
    k_alpha<1><<<(N + 255) / 256, 256, 0, stream>>>(sS, sD, row_ptr, edge_src, alpha, sden, N);
    k_role<<<(N * 64 + 255) / 256, 256, 0, stream>>>(role_ids, role_table, cat, N);
    k_aggb<64, false><<<(N + 7) / 8, 256, 0, stream>>>(hbf, alpha, sden, b3, ln3w, ln3b,
                                                       row_ptr, edge_src, cat, N, 128);

    // ---- MLP: cat[N,128] -> relu -> [N,64] -> out ----
    k_gemm2<128, 64, true, false><<<dim3(mb, 1), 256, 0, stream>>>(cat, p1w, p1b, z1, N, 64);
    k_gemm2<64, 64, false, false><<<dim3(mb, 1), 256, 0, stream>>>(z1, p2w, p2b, (float*)d_out, N, 64);
}

// Round 4
// 612.981 us; speedup vs baseline: 1.7457x; 1.1674x over previous
//
#include <hip/hip_runtime.h>
#include <math.h>

// ---------------------------------------------------------------------------
// TopologyAwareGATEncoder: 3x GATConv(+ELU+LN) -> concat role emb -> 2-layer MLP
// N=50000, E=400000 (+N self loops), IN=64, HID=64, HEADS=4
// GEMMs via bf16 MFMA (16x16x32), gather/aggregate via CSR + bf16 rows.
// ---------------------------------------------------------------------------

using short8 = __attribute__((ext_vector_type(8))) short;
using f32x4  = __attribute__((ext_vector_type(4))) float;

__device__ __forceinline__ unsigned short f2bf(float f) {
    unsigned int u = __builtin_bit_cast(unsigned int, f);
    u += 0x7fffu + ((u >> 16) & 1u);     // RN-even
    return (unsigned short)(u >> 16);
}
__device__ __forceinline__ float bf2f(unsigned short b) {
    unsigned int u = ((unsigned int)b) << 16;
    return __builtin_bit_cast(float, u);
}

// ---------------- fp32 -> bf16 convert (n multiple of 4) ----------------
__global__ void k_f2bf(const float* __restrict__ in, unsigned short* __restrict__ out,
                       int n) {
    int i = (blockIdx.x * 256 + threadIdx.x) * 4;
    if (i >= n) return;
    float4 v = *reinterpret_cast<const float4*>(in + i);
    ushort4 u;
    u.x = f2bf(v.x); u.y = f2bf(v.y); u.z = f2bf(v.z); u.w = f2bf(v.w);
    *reinterpret_cast<ushort4*>(out + i) = u;
}

// ---------------- CSR build ----------------
__global__ void k_count(const int* __restrict__ ei, int* __restrict__ deg,
                        int N, int E, int E2) {
    int i = blockIdx.x * 256 + threadIdx.x;
    if (i >= E2) return;
    int d = (i < E) ? ei[E + i] : (i - E);
    atomicAdd(&deg[d], 1);
}

__global__ __launch_bounds__(1024) void k_scan(const int* __restrict__ deg,
                                               int* __restrict__ row_ptr,
                                               int* __restrict__ cursor,
                                               int N, int E2) {
    __shared__ int sums[1024];
    int tid = threadIdx.x;
    int chunk = (N + 1023) / 1024;
    int st = tid * chunk;
    int en = min(N, st + chunk);
    int s = 0;
    for (int i = st; i < en; ++i) s += deg[i];
    sums[tid] = s;
    __syncthreads();
    for (int off = 1; off < 1024; off <<= 1) {
        int v = 0;
        if (tid >= off) v = sums[tid - off];
        __syncthreads();
        sums[tid] += v;
        __syncthreads();
    }
    int run = sums[tid] - s;  // exclusive prefix of this chunk
    for (int i = st; i < en; ++i) {
        row_ptr[i] = run;
        cursor[i] = run;
        run += deg[i];
    }
    if (tid == 0) row_ptr[N] = E2;
}

__global__ void k_fill(const int* __restrict__ ei, int* __restrict__ cursor,
                       int* __restrict__ edge_src, int N, int E, int E2) {
    int i = blockIdx.x * 256 + threadIdx.x;
    if (i >= E2) return;
    int s_, d_;
    if (i < E) { s_ = ei[i]; d_ = ei[E + i]; }
    else       { s_ = d_ = i - E; }
    int pos = atomicAdd(&cursor[d_], 1);
    edge_src[pos] = s_;
}

// ---------------- bf16 MFMA GEMM: C[M,NC] = A[M,K] @ W[NC,K]^T --------------
// A, W in bf16 row-major. 128 x BN tile, BK=32, 256 thr = 4 waves (2m x 2n).
// LDS row stride 40 ushorts (80B): 16B-aligned, <=2-way bank alias (free).
template <int K, int BN, bool RELU, bool BF16OUT>
__global__ __launch_bounds__(256) void k_gmfma(const unsigned short* __restrict__ A,
                                               const unsigned short* __restrict__ Wb,
                                               const float* __restrict__ bias,
                                               void* __restrict__ Cv,
                                               int M, int NC) {
    constexpr int NT = BN / 32;           // n-frags per wave
    constexpr int LDW = 40;               // LDS row stride in ushorts
    __shared__ unsigned short As[128 * LDW];
    __shared__ unsigned short Bs[BN * LDW];
    int tid = threadIdx.x;
    int lane = tid & 63, wid = tid >> 6;
    int wm = wid & 1, wn = wid >> 1;      // 2x2 wave grid
    int fr = lane & 15, fq = lane >> 4;
    int bm = blockIdx.x * 128, bn = blockIdx.y * BN;

    f32x4 acc[4][NT];
#pragma unroll
    for (int mt = 0; mt < 4; ++mt)
#pragma unroll
        for (int nt = 0; nt < NT; ++nt) acc[mt][nt] = f32x4{0.f, 0.f, 0.f, 0.f};

    for (int k0 = 0; k0 < K; k0 += 32) {
        // stage A tile: 128 rows x 4 chunks of 8 bf16
#pragma unroll
        for (int it = 0; it < 2; ++it) {
            int c = it * 256 + tid;
            int r = c >> 2, kq = c & 3;
            uint4 v = make_uint4(0u, 0u, 0u, 0u);
            if (bm + r < M)
                v = *reinterpret_cast<const uint4*>(A + (size_t)(bm + r) * K + k0 + kq * 8);
            *reinterpret_cast<uint4*>(&As[r * LDW + kq * 8]) = v;
        }
        // stage B tile: BN rows x 4 chunks
#pragma unroll
        for (int it = 0; it < BN / 64; ++it) {
            int c = it * 256 + tid;
            int r = c >> 2, kq = c & 3;
            uint4 v = *reinterpret_cast<const uint4*>(Wb + (size_t)(bn + r) * K + k0 + kq * 8);
            *reinterpret_cast<uint4*>(&Bs[r * LDW + kq * 8]) = v;
        }
        __syncthreads();
        short8 af[4], bfr[NT];
#pragma unroll
        for (int mt = 0; mt < 4; ++mt)
            af[mt] = *reinterpret_cast<const short8*>(&As[(wm * 64 + mt * 16 + fr) * LDW + fq * 8]);
#pragma unroll
        for (int nt = 0; nt < NT; ++nt)
            bfr[nt] = *reinterpret_cast<const short8*>(&Bs[(wn * (BN / 2) + nt * 16 + fr) * LDW + fq * 8]);
#pragma unroll
        for (int mt = 0; mt < 4; ++mt)
#pragma unroll
            for (int nt = 0; nt < NT; ++nt)
                acc[mt][nt] = __builtin_amdgcn_mfma_f32_16x16x32_bf16(
                    af[mt], bfr[nt], acc[mt][nt], 0, 0, 0);
        __syncthreads();
    }

    // epilogue: C row = fq*4+j, col = fr within each 16x16 fragment
#pragma unroll
    for (int nt = 0; nt < NT; ++nt) {
        int col = bn + wn * (BN / 2) + nt * 16 + fr;
        float bv = bias ? bias[col] : 0.f;
#pragma unroll
        for (int mt = 0; mt < 4; ++mt) {
#pragma unroll
            for (int j = 0; j < 4; ++j) {
                int row = bm + wm * 64 + mt * 16 + fq * 4 + j;
                if (row < M) {
                    float v = acc[mt][nt][j] + bv;
                    if (RELU) v = fmaxf(v, 0.f);
                    if constexpr (BF16OUT)
                        ((unsigned short*)Cv)[(size_t)row * NC + col] = f2bf(v);
                    else
                        ((float*)Cv)[(size_t)row * NC + col] = v;
                }
            }
        }
    }
}

// ---------------- per-(node,head) attention scores (bf16 h) ----------------
template <int H>
__global__ __launch_bounds__(256) void k_scores(const unsigned short* __restrict__ h,
                                                const float* __restrict__ a_s,
                                                const float* __restrict__ a_d,
                                                float* __restrict__ sS,
                                                float* __restrict__ sD, int N) {
    int wid = threadIdx.x >> 6;
    int lane = threadIdx.x & 63;
    int gw = blockIdx.x * 4 + wid;
    if (gw >= N * H) return;
    int n = gw / H, hh = gw % H;
    float v = bf2f(h[(size_t)n * (H * 64) + hh * 64 + lane]);
    float ds = v * a_s[hh * 64 + lane];
    float dd = v * a_d[hh * 64 + lane];
#pragma unroll
    for (int off = 32; off; off >>= 1) {
        ds += __shfl_down(ds, off);
        dd += __shfl_down(dd, off);
    }
    if (lane == 0) { sS[n * H + hh] = ds; sD[n * H + hh] = dd; }
}

// ---------------- per-(node,head) softmax weights: p=exp(e-m), sden=sum ----
template <int H>
__global__ void k_alpha(const float* __restrict__ sS, const float* __restrict__ sD,
                        const int* __restrict__ row_ptr, const int* __restrict__ edge_src,
                        float* __restrict__ alpha, float* __restrict__ sden, int NH) {
    int gid = blockIdx.x * 256 + threadIdx.x;
    if (gid >= NH) return;
    int n = gid / H;
    int h = gid - n * H;
    float sdn = sD[gid];
    int rs = row_ptr[n], re = row_ptr[n + 1];
    float m = -1e30f;
    for (int i = rs; i < re; ++i) {
        float e = sS[edge_src[i] * H + h] + sdn;
        e = e > 0.f ? e : 0.2f * e;          // leaky_relu 0.2
        alpha[i * H + h] = e;
        m = fmaxf(m, e);
    }
    float s = 0.f;
    for (int i = rs; i < re; ++i) {
        float p = __expf(alpha[i * H + h] - m);
        alpha[i * H + h] = p;
        s += p;
    }
    sden[gid] = s;
}

// ---------------- aggregation (bf16 gather) + bias + (ELU) + LayerNorm -----
// bf16 output (feeds next GEMM). 2 channels/thread.
template <int D, bool ELU>
__global__ __launch_bounds__(256) void k_aggb(
        const unsigned short* __restrict__ hbf,
        const float* __restrict__ alpha, const float* __restrict__ sden,
        const float* __restrict__ bias,
        const float* __restrict__ ln_w, const float* __restrict__ ln_b,
        const int* __restrict__ row_ptr, const int* __restrict__ edge_src,
        unsigned short* __restrict__ out, int N, int ostride) {
    constexpr int H = D / 64;
    constexpr int TPN = D / 2;
    constexpr int NPB = 256 / TPN;
    int tid = threadIdx.x;
    int n = blockIdx.x * NPB + tid / TPN;
    int t = tid % TPN;
    int c0 = 2 * t;
    int hh = c0 >> 6;
    if (n >= N) return;

    int rs = row_ptr[n], re = row_ptr[n + 1];
    float a0 = 0.f, a1 = 0.f;
    for (int i = rs; i < re; ++i) {
        int src = edge_src[i];
        float p = alpha[i * H + hh];
        unsigned int u = *reinterpret_cast<const unsigned int*>(
            hbf + (size_t)src * D + c0);
        a0 += p * bf2f((unsigned short)(u & 0xffffu));
        a1 += p * bf2f((unsigned short)(u >> 16));
    }
    float inv = 1.f / (sden[n * H + hh] + 1e-16f);
    float v0 = a0 * inv + bias[c0];
    float v1 = a1 * inv + bias[c0 + 1];
    if (ELU) {
        v0 = v0 > 0.f ? v0 : (__expf(v0) - 1.f);
        v1 = v1 > 0.f ? v1 : (__expf(v1) - 1.f);
    }

    // LayerNorm over D channels
    float sum = v0 + v1, sq = v0 * v0 + v1 * v1;
    if constexpr (TPN == 32) {
#pragma unroll
        for (int off = 1; off < 32; off <<= 1) {
            sum += __shfl_xor(sum, off);
            sq += __shfl_xor(sq, off);
        }
    } else {
#pragma unroll
        for (int off = 1; off < 64; off <<= 1) {
            sum += __shfl_xor(sum, off);
            sq += __shfl_xor(sq, off);
        }
        __shared__ float red[2][4];
        int w = tid >> 6;
        if ((tid & 63) == 0) { red[0][w] = sum; red[1][w] = sq; }
        __syncthreads();
        int wb = (tid >> 7) * 2;
        sum = red[0][wb] + red[0][wb + 1];
        sq = red[1][wb] + red[1][wb + 1];
    }
    float mu = sum / D;
    float var = fmaxf(sq / D - mu * mu, 0.f);
    float rstd = rsqrtf(var + 1e-5f);
    float y0 = (v0 - mu) * rstd * ln_w[c0] + ln_b[c0];
    float y1 = (v1 - mu) * rstd * ln_w[c0 + 1] + ln_b[c0 + 1];
    unsigned int packed = (unsigned int)f2bf(y0) | ((unsigned int)f2bf(y1) << 16);
    *reinterpret_cast<unsigned int*>(out + (size_t)n * ostride + c0) = packed;
}

// ---------------- role embedding into bf16 concat buffer ----------------
__global__ void k_role(const int* __restrict__ role_ids,
                       const float* __restrict__ role_table,
                       unsigned short* __restrict__ catb, int N) {
    int i = blockIdx.x * 256 + threadIdx.x;
    int n = i >> 6, c = i & 63;
    if (n >= N) return;
    catb[(size_t)n * 128 + 64 + c] = f2bf(role_table[role_ids[n] * 64 + c]);
}

// ---------------------------------------------------------------------------
extern "C" void kernel_launch(void* const* d_in, const int* in_sizes, int n_in,
                              void* d_out, int out_size, void* d_ws, size_t ws_size,
                              hipStream_t stream) {
    const float* x        = (const float*)d_in[0];
    const int*   ei       = (const int*)d_in[1];
    const int*   role_ids = (const int*)d_in[2];
    const float* W1  = (const float*)d_in[3];
    const float* a1s = (const float*)d_in[4];
    const float* a1d = (const float*)d_in[5];
    const float* b1  = (const float*)d_in[6];
    const float* W2  = (const float*)d_in[7];
    const float* a2s = (const float*)d_in[8];
    const float* a2d = (const float*)d_in[9];
    const float* b2  = (const float*)d_in[10];
    const float* W3  = (const float*)d_in[11];
    const float* a3s = (const float*)d_in[12];
    const float* a3d = (const float*)d_in[13];
    const float* b3  = (const float*)d_in[14];
    const float* ln1w = (const float*)d_in[15];
    const float* ln1b = (const float*)d_in[16];
    const float* ln2w = (const float*)d_in[17];
    const float* ln2b = (const float*)d_in[18];
    const float* ln3w = (const float*)d_in[19];
    const float* ln3b = (const float*)d_in[20];
    const float* role_table = (const float*)d_in[21];
    const float* p1w = (const float*)d_in[22];
    const float* p1b = (const float*)d_in[23];
    const float* p2w = (const float*)d_in[24];
    const float* p2b = (const float*)d_in[25];

    const int N = in_sizes[0] / 64;
    const int E = in_sizes[1] / 2;
    const int E2 = E + N;

    // workspace carve
    char* p = (char*)d_ws;
    auto carve = [&](size_t bytes) -> char* {
        char* r = p;
        p += (bytes + 255) & ~(size_t)255;
        return r;
    };
    int* deg      = (int*)carve((size_t)N * 4);
    int* row_ptr  = (int*)carve((size_t)(N + 1) * 4);
    int* cursor   = (int*)carve((size_t)N * 4);
    int* edge_src = (int*)carve((size_t)E2 * 4);
    float* sS     = (float*)carve((size_t)N * 4 * 4);
    float* sD     = (float*)carve((size_t)N * 4 * 4);
    float* alpha  = (float*)carve((size_t)E2 * 4 * 4);
    float* sden   = (float*)carve((size_t)N * 4 * 4);
    unsigned short* hbf  = (unsigned short*)carve((size_t)N * 256 * 2);  // GEMM out (pre-agg)
    unsigned short* hlnb = (unsigned short*)carve((size_t)N * 256 * 2);  // LN out (next GEMM A)
    unsigned short* catb = (unsigned short*)carve((size_t)N * 128 * 2);
    unsigned short* z1b  = (unsigned short*)carve((size_t)N * 64 * 2);
    unsigned short* xb   = (unsigned short*)carve((size_t)N * 64 * 2);
    unsigned short* W1b  = (unsigned short*)carve((size_t)256 * 64 * 2);
    unsigned short* W2b  = (unsigned short*)carve((size_t)256 * 256 * 2);
    unsigned short* W3b  = (unsigned short*)carve((size_t)64 * 256 * 2);
    unsigned short* p1wb = (unsigned short*)carve((size_t)64 * 128 * 2);
    unsigned short* p2wb = (unsigned short*)carve((size_t)64 * 64 * 2);

    // ---- converts ----
    auto cvt = [&](const float* src, unsigned short* dst, int n) {
        k_f2bf<<<(n / 4 + 255) / 256, 256, 0, stream>>>(src, dst, n);
    };
    cvt(x, xb, N * 64);
    cvt(W1, W1b, 256 * 64);
    cvt(W2, W2b, 256 * 256);
    cvt(W3, W3b, 64 * 256);
    cvt(p1w, p1wb, 64 * 128);
    cvt(p2w, p2wb, 64 * 64);

    // ---- CSR build ----
    hipMemsetAsync(deg, 0, (size_t)N * 4, stream);
    int eb = (E2 + 255) / 256;
    k_count<<<eb, 256, 0, stream>>>(ei, deg, N, E, E2);
    k_scan<<<1, 1024, 0, stream>>>(deg, row_ptr, cursor, N, E2);
    k_fill<<<eb, 256, 0, stream>>>(ei, cursor, edge_src, N, E, E2);

    int mb = (N + 127) / 128;

    // ---- layer 1: 64 -> 4x64 ----
    k_gmfma<64, 128, false, true><<<dim3(mb, 2), 256, 0, stream>>>(xb, W1b, nullptr, hbf, N, 256);
    k_scores<4><<<(N * 4 + 3) / 4, 256, 0, stream>>>(hbf, a1s, a1d, sS, sD, N);
    k_alpha<4><<<(N * 4 + 255) / 256, 256, 0, stream>>>(sS, sD, row_ptr, edge_src, alpha, sden, N * 4);
    k_aggb<256, true><<<(N + 1) / 2, 256, 0, stream>>>(hbf, alpha, sden, b1, ln1w, ln1b,
                                                       row_ptr, edge_src, hlnb, N, 256);

    // ---- layer 2: 256 -> 4x64 ----
    k_gmfma<256, 128, false, true><<<dim3(mb, 2), 256, 0, stream>>>(hlnb, W2b, nullptr, hbf, N, 256);
    k_scores<4><<<(N * 4 + 3) / 4, 256, 0, stream>>>(hbf, a2s, a2d, sS, sD, N);
    k_alpha<4><<<(N * 4 + 255) / 256, 256, 0, stream>>>(sS, sD, row_ptr, edge_src, alpha, sden, N * 4);
    k_aggb<256, true><<<(N + 1) / 2, 256, 0, stream>>>(hbf, alpha, sden, b2, ln2w, ln2b,
                                                       row_ptr, edge_src, hlnb, N, 256);

    // ---- layer 3: 256 -> 64 (1 head, no concat) ----
    k_gmfma<256, 64, false, true><<<dim3(mb, 1), 256, 0, stream>>>(hlnb, W3b, nullptr, hbf, N, 64);
    k_scores<1><<<(N + 3) / 4, 256, 0, stream>>>(hbf, a3s, a3d, sS, sD, N);
    k_alpha<1><<<(N + 255) / 256, 256, 0, stream>>>(sS, sD, row_ptr, edge_src, alpha, sden, N);
    k_role<<<(N * 64 + 255) / 256, 256, 0, stream>>>(role_ids, role_table, catb, N);
    k_aggb<64, false><<<(N + 7) / 8, 256, 0, stream>>>(hbf, alpha, sden, b3, ln3w, ln3b,
                                                       row_ptr, edge_src, catb, N, 128);

    // ---- MLP: cat[N,128] -> relu -> [N,64] -> out ----
    k_gmfma<128, 64, true, true><<<dim3(mb, 1), 256, 0, stream>>>(catb, p1wb, p1b, z1b, N, 64);
    k_gmfma<64, 64, false, false><<<dim3(mb, 1), 256, 0, stream>>>(z1b, p2wb, p2b, (float*)d_out, N, 64);
}

// Round 5
// 511.079 us; speedup vs baseline: 2.0938x; 1.1994x over previous
//
#include <hip/hip_runtime.h>
#include <math.h>

// ---------------------------------------------------------------------------
// TopologyAwareGATEncoder: 3x GATConv(+ELU+LN) -> concat role emb -> 2-layer MLP
// N=50000, E=400000 (+N self loops), IN=64, HID=64, HEADS=4
// GEMMs via bf16 MFMA (16x16x32), gather/aggregate via CSR + bf16 rows.
// ---------------------------------------------------------------------------

using short8 = __attribute__((ext_vector_type(8))) short;
using f32x4  = __attribute__((ext_vector_type(4))) float;

__device__ __forceinline__ unsigned short f2bf(float f) {
    unsigned int u = __builtin_bit_cast(unsigned int, f);
    u += 0x7fffu + ((u >> 16) & 1u);     // RN-even
    return (unsigned short)(u >> 16);
}
__device__ __forceinline__ float bf2f(unsigned short b) {
    unsigned int u = ((unsigned int)b) << 16;
    return __builtin_bit_cast(float, u);
}

// ---------------- fp32 -> bf16 convert (n multiple of 4) ----------------
__global__ void k_f2bf(const float* __restrict__ in, unsigned short* __restrict__ out,
                       int n) {
    int i = (blockIdx.x * 256 + threadIdx.x) * 4;
    if (i >= n) return;
    float4 v = *reinterpret_cast<const float4*>(in + i);
    ushort4 u;
    u.x = f2bf(v.x); u.y = f2bf(v.y); u.z = f2bf(v.z); u.w = f2bf(v.w);
    *reinterpret_cast<ushort4*>(out + i) = u;
}

// ---------------- CSR build ----------------
__global__ void k_count(const int* __restrict__ ei, int* __restrict__ deg,
                        int N, int E, int E2) {
    int i = blockIdx.x * 256 + threadIdx.x;
    if (i >= E2) return;
    int d = (i < E) ? ei[E + i] : (i - E);
    atomicAdd(&deg[d], 1);
}

// block-wide inclusive scan of one int per thread (256 threads)
__device__ __forceinline__ int blk_scan_incl(int v, int tid) {
    int lane = tid & 63, w = tid >> 6;
#pragma unroll
    for (int off = 1; off < 64; off <<= 1) {
        int u = __shfl_up(v, off);
        if (lane >= off) v += u;
    }
    __shared__ int wsum[4];
    if (lane == 63) wsum[w] = v;
    __syncthreads();
    int add = 0;
#pragma unroll
    for (int k = 0; k < 4; ++k)
        if (k < w) add += wsum[k];
    return v + add;
}

__global__ __launch_bounds__(256) void k_bsum(const int* __restrict__ deg,
                                              int* __restrict__ bsum, int N) {
    int i = blockIdx.x * 256 + threadIdx.x;
    int v = (i < N) ? deg[i] : 0;
#pragma unroll
    for (int off = 32; off; off >>= 1) v += __shfl_down(v, off);
    __shared__ int ws[4];
    if ((threadIdx.x & 63) == 0) ws[threadIdx.x >> 6] = v;
    __syncthreads();
    if (threadIdx.x == 0) bsum[blockIdx.x] = ws[0] + ws[1] + ws[2] + ws[3];
}

__global__ __launch_bounds__(256) void k_bscan(const int* __restrict__ bsum,
                                               int* __restrict__ boff, int nb) {
    int t = threadIdx.x;
    int v = (t < nb) ? bsum[t] : 0;
    int incl = blk_scan_incl(v, t);
    if (t < nb) boff[t] = incl - v;      // exclusive
}

__global__ __launch_bounds__(256) void k_scatter(const int* __restrict__ deg,
                                                 const int* __restrict__ boff,
                                                 int* __restrict__ row_ptr,
                                                 int* __restrict__ cursor,
                                                 int N, int E2) {
    int tid = threadIdx.x;
    int i = blockIdx.x * 256 + tid;
    int d = (i < N) ? deg[i] : 0;
    int incl = blk_scan_incl(d, tid);
    int ex = incl - d + boff[blockIdx.x];
    if (i < N) { row_ptr[i] = ex; cursor[i] = ex; }
    if (i == 0) row_ptr[N] = E2;
}

__global__ void k_fill(const int* __restrict__ ei, int* __restrict__ cursor,
                       int* __restrict__ edge_src, int N, int E, int E2) {
    int i = blockIdx.x * 256 + threadIdx.x;
    if (i >= E2) return;
    int s_, d_;
    if (i < E) { s_ = ei[i]; d_ = ei[E + i]; }
    else       { s_ = d_ = i - E; }
    int pos = atomicAdd(&cursor[d_], 1);
    edge_src[pos] = s_;
}

// ---------------- bf16 MFMA GEMM: C[M,NC] = A[M,K] @ W[NC,K]^T --------------
// A, W in bf16 row-major. 128 x BN tile, BK=32, 256 thr = 4 waves (2m x 2n).
// LDS row stride 40 ushorts (80B): 16B-aligned, <=2-way bank alias (free).
template <int K, int BN, bool RELU, bool BF16OUT>
__global__ __launch_bounds__(256) void k_gmfma(const unsigned short* __restrict__ A,
                                               const unsigned short* __restrict__ Wb,
                                               const float* __restrict__ bias,
                                               void* __restrict__ Cv,
                                               int M, int NC) {
    constexpr int NT = BN / 32;           // n-frags per wave
    constexpr int LDW = 40;               // LDS row stride in ushorts
    __shared__ unsigned short As[128 * LDW];
    __shared__ unsigned short Bs[BN * LDW];
    int tid = threadIdx.x;
    int lane = tid & 63, wid = tid >> 6;
    int wm = wid & 1, wn = wid >> 1;      // 2x2 wave grid
    int fr = lane & 15, fq = lane >> 4;
    int bm = blockIdx.x * 128, bn = blockIdx.y * BN;

    f32x4 acc[4][NT];
#pragma unroll
    for (int mt = 0; mt < 4; ++mt)
#pragma unroll
        for (int nt = 0; nt < NT; ++nt) acc[mt][nt] = f32x4{0.f, 0.f, 0.f, 0.f};

    for (int k0 = 0; k0 < K; k0 += 32) {
        // stage A tile: 128 rows x 4 chunks of 8 bf16
#pragma unroll
        for (int it = 0; it < 2; ++it) {
            int c = it * 256 + tid;
            int r = c >> 2, kq = c & 3;
            uint4 v = make_uint4(0u, 0u, 0u, 0u);
            if (bm + r < M)
                v = *reinterpret_cast<const uint4*>(A + (size_t)(bm + r) * K + k0 + kq * 8);
            *reinterpret_cast<uint4*>(&As[r * LDW + kq * 8]) = v;
        }
        // stage B tile: BN rows x 4 chunks
#pragma unroll
        for (int it = 0; it < BN / 64; ++it) {
            int c = it * 256 + tid;
            int r = c >> 2, kq = c & 3;
            uint4 v = *reinterpret_cast<const uint4*>(Wb + (size_t)(bn + r) * K + k0 + kq * 8);
            *reinterpret_cast<uint4*>(&Bs[r * LDW + kq * 8]) = v;
        }
        __syncthreads();
        short8 af[4], bfr[NT];
#pragma unroll
        for (int mt = 0; mt < 4; ++mt)
            af[mt] = *reinterpret_cast<const short8*>(&As[(wm * 64 + mt * 16 + fr) * LDW + fq * 8]);
#pragma unroll
        for (int nt = 0; nt < NT; ++nt)
            bfr[nt] = *reinterpret_cast<const short8*>(&Bs[(wn * (BN / 2) + nt * 16 + fr) * LDW + fq * 8]);
#pragma unroll
        for (int mt = 0; mt < 4; ++mt)
#pragma unroll
            for (int nt = 0; nt < NT; ++nt)
                acc[mt][nt] = __builtin_amdgcn_mfma_f32_16x16x32_bf16(
                    af[mt], bfr[nt], acc[mt][nt], 0, 0, 0);
        __syncthreads();
    }

    // epilogue: C row = fq*4+j, col = fr within each 16x16 fragment
#pragma unroll
    for (int nt = 0; nt < NT; ++nt) {
        int col = bn + wn * (BN / 2) + nt * 16 + fr;
        float bv = bias ? bias[col] : 0.f;
#pragma unroll
        for (int mt = 0; mt < 4; ++mt) {
#pragma unroll
            for (int j = 0; j < 4; ++j) {
                int row = bm + wm * 64 + mt * 16 + fq * 4 + j;
                if (row < M) {
                    float v = acc[mt][nt][j] + bv;
                    if (RELU) v = fmaxf(v, 0.f);
                    if constexpr (BF16OUT)
                        ((unsigned short*)Cv)[(size_t)row * NC + col] = f2bf(v);
                    else
                        ((float*)Cv)[(size_t)row * NC + col] = v;
                }
            }
        }
    }
}

// ---------------- per-(node,head) attention scores (bf16 h) ----------------
template <int H>
__global__ __launch_bounds__(256) void k_scores(const unsigned short* __restrict__ h,
                                                const float* __restrict__ a_s,
                                                const float* __restrict__ a_d,
                                                float* __restrict__ sS,
                                                float* __restrict__ sD, int N) {
    int wid = threadIdx.x >> 6;
    int lane = threadIdx.x & 63;
    int gw = blockIdx.x * 4 + wid;
    if (gw >= N * H) return;
    int n = gw / H, hh = gw % H;
    float v = bf2f(h[(size_t)n * (H * 64) + hh * 64 + lane]);
    float ds = v * a_s[hh * 64 + lane];
    float dd = v * a_d[hh * 64 + lane];
#pragma unroll
    for (int off = 32; off; off >>= 1) {
        ds += __shfl_down(ds, off);
        dd += __shfl_down(dd, off);
    }
    if (lane == 0) { sS[n * H + hh] = ds; sD[n * H + hh] = dd; }
}

// ---------------- per-(node,head) softmax weights: p=exp(e-m), sden=sum ----
template <int H>
__global__ void k_alpha(const float* __restrict__ sS, const float* __restrict__ sD,
                        const int* __restrict__ row_ptr, const int* __restrict__ edge_src,
                        float* __restrict__ alpha, float* __restrict__ sden, int NH) {
    int gid = blockIdx.x * 256 + threadIdx.x;
    if (gid >= NH) return;
    int n = gid / H;
    int h = gid - n * H;
    float sdn = sD[gid];
    int rs = row_ptr[n], re = row_ptr[n + 1];
    float m = -1e30f;
    for (int i = rs; i < re; ++i) {
        float e = sS[edge_src[i] * H + h] + sdn;
        e = e > 0.f ? e : 0.2f * e;          // leaky_relu 0.2
        alpha[i * H + h] = e;
        m = fmaxf(m, e);
    }
    float s = 0.f;
    for (int i = rs; i < re; ++i) {
        float p = __expf(alpha[i * H + h] - m);
        alpha[i * H + h] = p;
        s += p;
    }
    sden[gid] = s;
}

// ---------------- aggregation (bf16 gather) + bias + (ELU) + LayerNorm -----
// bf16 output (feeds next GEMM). 2 channels/thread.
template <int D, bool ELU>
__global__ __launch_bounds__(256) void k_aggb(
        const unsigned short* __restrict__ hbf,
        const float* __restrict__ alpha, const float* __restrict__ sden,
        const float* __restrict__ bias,
        const float* __restrict__ ln_w, const float* __restrict__ ln_b,
        const int* __restrict__ row_ptr, const int* __restrict__ edge_src,
        unsigned short* __restrict__ out, int N, int ostride) {
    constexpr int H = D / 64;
    constexpr int TPN = D / 2;
    constexpr int NPB = 256 / TPN;
    int tid = threadIdx.x;
    int n = blockIdx.x * NPB + tid / TPN;
    int t = tid % TPN;
    int c0 = 2 * t;
    int hh = c0 >> 6;
    if (n >= N) return;

    int rs = row_ptr[n], re = row_ptr[n + 1];
    float a0 = 0.f, a1 = 0.f;
    for (int i = rs; i < re; ++i) {
        int src = edge_src[i];
        float p = alpha[i * H + hh];
        unsigned int u = *reinterpret_cast<const unsigned int*>(
            hbf + (size_t)src * D + c0);
        a0 += p * bf2f((unsigned short)(u & 0xffffu));
        a1 += p * bf2f((unsigned short)(u >> 16));
    }
    float inv = 1.f / (sden[n * H + hh] + 1e-16f);
    float v0 = a0 * inv + bias[c0];
    float v1 = a1 * inv + bias[c0 + 1];
    if (ELU) {
        v0 = v0 > 0.f ? v0 : (__expf(v0) - 1.f);
        v1 = v1 > 0.f ? v1 : (__expf(v1) - 1.f);
    }

    // LayerNorm over D channels
    float sum = v0 + v1, sq = v0 * v0 + v1 * v1;
    if constexpr (TPN == 32) {
#pragma unroll
        for (int off = 1; off < 32; off <<= 1) {
            sum += __shfl_xor(sum, off);
            sq += __shfl_xor(sq, off);
        }
    } else {
#pragma unroll
        for (int off = 1; off < 64; off <<= 1) {
            sum += __shfl_xor(sum, off);
            sq += __shfl_xor(sq, off);
        }
        __shared__ float red[2][4];
        int w = tid >> 6;
        if ((tid & 63) == 0) { red[0][w] = sum; red[1][w] = sq; }
        __syncthreads();
        int wb = (tid >> 7) * 2;
        sum = red[0][wb] + red[0][wb + 1];
        sq = red[1][wb] + red[1][wb + 1];
    }
    float mu = sum / D;
    float var = fmaxf(sq / D - mu * mu, 0.f);
    float rstd = rsqrtf(var + 1e-5f);
    float y0 = (v0 - mu) * rstd * ln_w[c0] + ln_b[c0];
    float y1 = (v1 - mu) * rstd * ln_w[c0 + 1] + ln_b[c0 + 1];
    unsigned int packed = (unsigned int)f2bf(y0) | ((unsigned int)f2bf(y1) << 16);
    *reinterpret_cast<unsigned int*>(out + (size_t)n * ostride + c0) = packed;
}

// ---------------- role embedding into bf16 concat buffer ----------------
__global__ void k_role(const int* __restrict__ role_ids,
                       const float* __restrict__ role_table,
                       unsigned short* __restrict__ catb, int N) {
    int i = blockIdx.x * 256 + threadIdx.x;
    int n = i >> 6, c = i & 63;
    if (n >= N) return;
    catb[(size_t)n * 128 + 64 + c] = f2bf(role_table[role_ids[n] * 64 + c]);
}

// ---------------------------------------------------------------------------
extern "C" void kernel_launch(void* const* d_in, const int* in_sizes, int n_in,
                              void* d_out, int out_size, void* d_ws, size_t ws_size,
                              hipStream_t stream) {
    const float* x        = (const float*)d_in[0];
    const int*   ei       = (const int*)d_in[1];
    const int*   role_ids = (const int*)d_in[2];
    const float* W1  = (const float*)d_in[3];
    const float* a1s = (const float*)d_in[4];
    const float* a1d = (const float*)d_in[5];
    const float* b1  = (const float*)d_in[6];
    const float* W2  = (const float*)d_in[7];
    const float* a2s = (const float*)d_in[8];
    const float* a2d = (const float*)d_in[9];
    const float* b2  = (const float*)d_in[10];
    const float* W3  = (const float*)d_in[11];
    const float* a3s = (const float*)d_in[12];
    const float* a3d = (const float*)d_in[13];
    const float* b3  = (const float*)d_in[14];
    const float* ln1w = (const float*)d_in[15];
    const float* ln1b = (const float*)d_in[16];
    const float* ln2w = (const float*)d_in[17];
    const float* ln2b = (const float*)d_in[18];
    const float* ln3w = (const float*)d_in[19];
    const float* ln3b = (const float*)d_in[20];
    const float* role_table = (const float*)d_in[21];
    const float* p1w = (const float*)d_in[22];
    const float* p1b = (const float*)d_in[23];
    const float* p2w = (const float*)d_in[24];
    const float* p2b = (const float*)d_in[25];

    const int N = in_sizes[0] / 64;
    const int E = in_sizes[1] / 2;
    const int E2 = E + N;

    // workspace carve
    char* p = (char*)d_ws;
    auto carve = [&](size_t bytes) -> char* {
        char* r = p;
        p += (bytes + 255) & ~(size_t)255;
        return r;
    };
    int* deg      = (int*)carve((size_t)N * 4);
    int* row_ptr  = (int*)carve((size_t)(N + 1) * 4);
    int* cursor   = (int*)carve((size_t)N * 4);
    int* edge_src = (int*)carve((size_t)E2 * 4);
    int* bsum     = (int*)carve((size_t)1024 * 4);
    int* boff     = (int*)carve((size_t)1024 * 4);
    float* sS     = (float*)carve((size_t)N * 4 * 4);
    float* sD     = (float*)carve((size_t)N * 4 * 4);
    float* alpha  = (float*)carve((size_t)E2 * 4 * 4);
    float* sden   = (float*)carve((size_t)N * 4 * 4);
    unsigned short* hbf  = (unsigned short*)carve((size_t)N * 256 * 2);  // GEMM out (pre-agg)
    unsigned short* hlnb = (unsigned short*)carve((size_t)N * 256 * 2);  // LN out (next GEMM A)
    unsigned short* catb = (unsigned short*)carve((size_t)N * 128 * 2);
    unsigned short* z1b  = (unsigned short*)carve((size_t)N * 64 * 2);
    unsigned short* xb   = (unsigned short*)carve((size_t)N * 64 * 2);
    unsigned short* W1b  = (unsigned short*)carve((size_t)256 * 64 * 2);
    unsigned short* W2b  = (unsigned short*)carve((size_t)256 * 256 * 2);
    unsigned short* W3b  = (unsigned short*)carve((size_t)64 * 256 * 2);
    unsigned short* p1wb = (unsigned short*)carve((size_t)64 * 128 * 2);
    unsigned short* p2wb = (unsigned short*)carve((size_t)64 * 64 * 2);

    // ---- converts ----
    auto cvt = [&](const float* src, unsigned short* dst, int n) {
        k_f2bf<<<(n / 4 + 255) / 256, 256, 0, stream>>>(src, dst, n);
    };
    cvt(x, xb, N * 64);
    cvt(W1, W1b, 256 * 64);
    cvt(W2, W2b, 256 * 256);
    cvt(W3, W3b, 64 * 256);
    cvt(p1w, p1wb, 64 * 128);
    cvt(p2w, p2wb, 64 * 64);

    // ---- CSR build (parallel 3-kernel scan) ----
    hipMemsetAsync(deg, 0, (size_t)N * 4, stream);
    int eb = (E2 + 255) / 256;
    int nb = (N + 255) / 256;
    k_count<<<eb, 256, 0, stream>>>(ei, deg, N, E, E2);
    k_bsum<<<nb, 256, 0, stream>>>(deg, bsum, N);
    k_bscan<<<1, 256, 0, stream>>>(bsum, boff, nb);
    k_scatter<<<nb, 256, 0, stream>>>(deg, boff, row_ptr, cursor, N, E2);
    k_fill<<<eb, 256, 0, stream>>>(ei, cursor, edge_src, N, E, E2);

    int mb = (N + 127) / 128;

    // ---- layer 1: 64 -> 4x64 ----
    k_gmfma<64, 128, false, true><<<dim3(mb, 2), 256, 0, stream>>>(xb, W1b, nullptr, hbf, N, 256);
    k_scores<4><<<(N * 4 + 3) / 4, 256, 0, stream>>>(hbf, a1s, a1d, sS, sD, N);
    k_alpha<4><<<(N * 4 + 255) / 256, 256, 0, stream>>>(sS, sD, row_ptr, edge_src, alpha, sden, N * 4);
    k_aggb<256, true><<<(N + 1) / 2, 256, 0, stream>>>(hbf, alpha, sden, b1, ln1w, ln1b,
                                                       row_ptr, edge_src, hlnb, N, 256);

    // ---- layer 2: 256 -> 4x64 ----
    k_gmfma<256, 128, false, true><<<dim3(mb, 2), 256, 0, stream>>>(hlnb, W2b, nullptr, hbf, N, 256);
    k_scores<4><<<(N * 4 + 3) / 4, 256, 0, stream>>>(hbf, a2s, a2d, sS, sD, N);
    k_alpha<4><<<(N * 4 + 255) / 256, 256, 0, stream>>>(sS, sD, row_ptr, edge_src, alpha, sden, N * 4);
    k_aggb<256, true><<<(N + 1) / 2, 256, 0, stream>>>(hbf, alpha, sden, b2, ln2w, ln2b,
                                                       row_ptr, edge_src, hlnb, N, 256);

    // ---- layer 3: 256 -> 64 (1 head, no concat) ----
    k_gmfma<256, 64, false, true><<<dim3(mb, 1), 256, 0, stream>>>(hlnb, W3b, nullptr, hbf, N, 64);
    k_scores<1><<<(N + 3) / 4, 256, 0, stream>>>(hbf, a3s, a3d, sS, sD, N);
    k_alpha<1><<<(N + 255) / 256, 256, 0, stream>>>(sS, sD, row_ptr, edge_src, alpha, sden, N);
    k_role<<<(N * 64 + 255) / 256, 256, 0, stream>>>(role_ids, role_table, catb, N);
    k_aggb<64, false><<<(N + 7) / 8, 256, 0, stream>>>(hbf, alpha, sden, b3, ln3w, ln3b,
                                                       row_ptr, edge_src, catb, N, 128);

    // ---- MLP: cat[N,128] -> relu -> [N,64] -> out ----
    k_gmfma<128, 64, true, true><<<dim3(mb, 1), 256, 0, stream>>>(catb, p1wb, p1b, z1b, N, 64);
    k_gmfma<64, 64, false, false><<<dim3(mb, 1), 256, 0, stream>>>(z1b, p2wb, p2b, (float*)d_out, N, 64);
}

// Round 6
// 376.133 us; speedup vs baseline: 2.8450x; 1.3588x over previous
//
#include <hip/hip_runtime.h>
#include <math.h>

// ---------------------------------------------------------------------------
// TopologyAwareGATEncoder: 3x GATConv(+ELU+LN) -> concat role emb -> 2-layer MLP
// N=50000, E=400000 (+N self loops), IN=64, HID=64, HEADS=4
// GEMMs via bf16 MFMA (16x16x32), gather/aggregate via CSR + bf16 rows.
// ---------------------------------------------------------------------------

using short8 = __attribute__((ext_vector_type(8))) short;
using f32x4  = __attribute__((ext_vector_type(4))) float;

__device__ __forceinline__ unsigned short f2bf(float f) {
    unsigned int u = __builtin_bit_cast(unsigned int, f);
    u += 0x7fffu + ((u >> 16) & 1u);     // RN-even
    return (unsigned short)(u >> 16);
}
__device__ __forceinline__ float bf2f(unsigned int b16) {
    unsigned int u = b16 << 16;
    return __builtin_bit_cast(float, u);
}

// ---------------- fp32 -> bf16 convert (n multiple of 4) ----------------
__global__ void k_f2bf(const float* __restrict__ in, unsigned short* __restrict__ out,
                       int n) {
    int i = (blockIdx.x * 256 + threadIdx.x) * 4;
    if (i >= n) return;
    float4 v = *reinterpret_cast<const float4*>(in + i);
    ushort4 u;
    u.x = f2bf(v.x); u.y = f2bf(v.y); u.z = f2bf(v.z); u.w = f2bf(v.w);
    *reinterpret_cast<ushort4*>(out + i) = u;
}

// ---------------- CSR build ----------------
__global__ void k_count(const int* __restrict__ ei, int* __restrict__ deg,
                        int N, int E, int E2) {
    int i = blockIdx.x * 256 + threadIdx.x;
    if (i >= E2) return;
    int d = (i < E) ? ei[E + i] : (i - E);
    atomicAdd(&deg[d], 1);
}

// block-wide inclusive scan of one int per thread (256 threads)
__device__ __forceinline__ int blk_scan_incl(int v, int tid) {
    int lane = tid & 63, w = tid >> 6;
#pragma unroll
    for (int off = 1; off < 64; off <<= 1) {
        int u = __shfl_up(v, off);
        if (lane >= off) v += u;
    }
    __shared__ int wsum[4];
    if (lane == 63) wsum[w] = v;
    __syncthreads();
    int add = 0;
#pragma unroll
    for (int k = 0; k < 4; ++k)
        if (k < w) add += wsum[k];
    return v + add;
}

__global__ __launch_bounds__(256) void k_bsum(const int* __restrict__ deg,
                                              int* __restrict__ bsum, int N) {
    int i = blockIdx.x * 256 + threadIdx.x;
    int v = (i < N) ? deg[i] : 0;
#pragma unroll
    for (int off = 32; off; off >>= 1) v += __shfl_down(v, off);
    __shared__ int ws[4];
    if ((threadIdx.x & 63) == 0) ws[threadIdx.x >> 6] = v;
    __syncthreads();
    if (threadIdx.x == 0) bsum[blockIdx.x] = ws[0] + ws[1] + ws[2] + ws[3];
}

__global__ __launch_bounds__(256) void k_bscan(const int* __restrict__ bsum,
                                               int* __restrict__ boff, int nb) {
    int t = threadIdx.x;
    int v = (t < nb) ? bsum[t] : 0;
    int incl = blk_scan_incl(v, t);
    if (t < nb) boff[t] = incl - v;      // exclusive
}

__global__ __launch_bounds__(256) void k_scatter(const int* __restrict__ deg,
                                                 const int* __restrict__ boff,
                                                 int* __restrict__ row_ptr,
                                                 int* __restrict__ cursor,
                                                 int N, int E2) {
    int tid = threadIdx.x;
    int i = blockIdx.x * 256 + tid;
    int d = (i < N) ? deg[i] : 0;
    int incl = blk_scan_incl(d, tid);
    int ex = incl - d + boff[blockIdx.x];
    if (i < N) { row_ptr[i] = ex; cursor[i] = ex; }
    if (i == 0) row_ptr[N] = E2;
}

__global__ void k_fill(const int* __restrict__ ei, int* __restrict__ cursor,
                       int* __restrict__ edge_src, int N, int E, int E2) {
    int i = blockIdx.x * 256 + threadIdx.x;
    if (i >= E2) return;
    int s_, d_;
    if (i < E) { s_ = ei[i]; d_ = ei[E + i]; }
    else       { s_ = d_ = i - E; }
    int pos = atomicAdd(&cursor[d_], 1);
    edge_src[pos] = s_;
}

// ---------------- bf16 MFMA GEMM: C[M,NC] = A[M,K] @ W[NC,K]^T --------------
// A, W in bf16 row-major. 128 x BN tile, BK=32, 256 thr = 4 waves (2m x 2n).
// LDS row stride 40 ushorts (80B): 16B-aligned, <=2-way bank alias (free).
template <int K, int BN, bool RELU, bool BF16OUT>
__global__ __launch_bounds__(256) void k_gmfma(const unsigned short* __restrict__ A,
                                               const unsigned short* __restrict__ Wb,
                                               const float* __restrict__ bias,
                                               void* __restrict__ Cv,
                                               int M, int NC) {
    constexpr int NT = BN / 32;           // n-frags per wave
    constexpr int LDW = 40;               // LDS row stride in ushorts
    __shared__ unsigned short As[128 * LDW];
    __shared__ unsigned short Bs[BN * LDW];
    int tid = threadIdx.x;
    int lane = tid & 63, wid = tid >> 6;
    int wm = wid & 1, wn = wid >> 1;      // 2x2 wave grid
    int fr = lane & 15, fq = lane >> 4;
    int bm = blockIdx.x * 128, bn = blockIdx.y * BN;

    f32x4 acc[4][NT];
#pragma unroll
    for (int mt = 0; mt < 4; ++mt)
#pragma unroll
        for (int nt = 0; nt < NT; ++nt) acc[mt][nt] = f32x4{0.f, 0.f, 0.f, 0.f};

    for (int k0 = 0; k0 < K; k0 += 32) {
        // stage A tile: 128 rows x 4 chunks of 8 bf16
#pragma unroll
        for (int it = 0; it < 2; ++it) {
            int c = it * 256 + tid;
            int r = c >> 2, kq = c & 3;
            uint4 v = make_uint4(0u, 0u, 0u, 0u);
            if (bm + r < M)
                v = *reinterpret_cast<const uint4*>(A + (size_t)(bm + r) * K + k0 + kq * 8);
            *reinterpret_cast<uint4*>(&As[r * LDW + kq * 8]) = v;
        }
        // stage B tile: BN rows x 4 chunks
#pragma unroll
        for (int it = 0; it < BN / 64; ++it) {
            int c = it * 256 + tid;
            int r = c >> 2, kq = c & 3;
            uint4 v = *reinterpret_cast<const uint4*>(Wb + (size_t)(bn + r) * K + k0 + kq * 8);
            *reinterpret_cast<uint4*>(&Bs[r * LDW + kq * 8]) = v;
        }
        __syncthreads();
        short8 af[4], bfr[NT];
#pragma unroll
        for (int mt = 0; mt < 4; ++mt)
            af[mt] = *reinterpret_cast<const short8*>(&As[(wm * 64 + mt * 16 + fr) * LDW + fq * 8]);
#pragma unroll
        for (int nt = 0; nt < NT; ++nt)
            bfr[nt] = *reinterpret_cast<const short8*>(&Bs[(wn * (BN / 2) + nt * 16 + fr) * LDW + fq * 8]);
#pragma unroll
        for (int mt = 0; mt < 4; ++mt)
#pragma unroll
            for (int nt = 0; nt < NT; ++nt)
                acc[mt][nt] = __builtin_amdgcn_mfma_f32_16x16x32_bf16(
                    af[mt], bfr[nt], acc[mt][nt], 0, 0, 0);
        __syncthreads();
    }

    // epilogue: C row = fq*4+j, col = fr within each 16x16 fragment
#pragma unroll
    for (int nt = 0; nt < NT; ++nt) {
        int col = bn + wn * (BN / 2) + nt * 16 + fr;
        float bv = bias ? bias[col] : 0.f;
#pragma unroll
        for (int mt = 0; mt < 4; ++mt) {
#pragma unroll
            for (int j = 0; j < 4; ++j) {
                int row = bm + wm * 64 + mt * 16 + fq * 4 + j;
                if (row < M) {
                    float v = acc[mt][nt][j] + bv;
                    if (RELU) v = fmaxf(v, 0.f);
                    if constexpr (BF16OUT)
                        ((unsigned short*)Cv)[(size_t)row * NC + col] = f2bf(v);
                    else
                        ((float*)Cv)[(size_t)row * NC + col] = v;
                }
            }
        }
    }
}

// ---------------- per-(node,head) attention scores (bf16 h) ----------------
template <int H>
__global__ __launch_bounds__(256) void k_scores(const unsigned short* __restrict__ h,
                                                const float* __restrict__ a_s,
                                                const float* __restrict__ a_d,
                                                float* __restrict__ sS,
                                                float* __restrict__ sD, int N) {
    int wid = threadIdx.x >> 6;
    int lane = threadIdx.x & 63;
    int gw = blockIdx.x * 4 + wid;
    if (gw >= N * H) return;
    int n = gw / H, hh = gw % H;
    float v = bf2f(h[(size_t)n * (H * 64) + hh * 64 + lane]);
    float ds = v * a_s[hh * 64 + lane];
    float dd = v * a_d[hh * 64 + lane];
#pragma unroll
    for (int off = 32; off; off >>= 1) {
        ds += __shfl_down(ds, off);
        dd += __shfl_down(dd, off);
    }
    if (lane == 0) { sS[n * H + hh] = ds; sD[n * H + hh] = dd; }
}

// -------- per-(node,head) softmax weights: rec = (src, p=exp(e-m)), sden ----
template <int H>
__global__ void k_alpha(const float* __restrict__ sS, const float* __restrict__ sD,
                        const int* __restrict__ row_ptr, const int* __restrict__ edge_src,
                        int2* __restrict__ rec, float* __restrict__ sden, int NH) {
    int gid = blockIdx.x * 256 + threadIdx.x;
    if (gid >= NH) return;
    int n = gid / H;
    int h = gid - n * H;
    float sdn = sD[gid];
    int rs = row_ptr[n], re = row_ptr[n + 1];
    float m = -1e30f;
    for (int i = rs; i < re; ++i) {
        int src = edge_src[i];
        float e = sS[src * H + h] + sdn;
        e = e > 0.f ? e : 0.2f * e;          // leaky_relu 0.2
        rec[i * H + h] = make_int2(src, __float_as_int(e));
        m = fmaxf(m, e);
    }
    float s = 0.f;
    for (int i = rs; i < re; ++i) {
        int2 r = rec[i * H + h];
        float p = __expf(__int_as_float(r.y) - m);
        rec[i * H + h].y = __float_as_int(p);
        s += p;
    }
    sden[gid] = s;
}

// ---------------- aggregation (bf16 gather) + bias + (ELU) + LayerNorm -----
// 8 channels/thread (uint4 gather). TPN = D/8 threads per node (32 or 8);
// LN reduction fits in a <=32-lane shuffle group: no LDS, no barrier.
template <int D, bool ELU>
__global__ __launch_bounds__(256) void k_aggb(
        const unsigned short* __restrict__ hbf,
        const int2* __restrict__ rec, const float* __restrict__ sden,
        const float* __restrict__ bias,
        const float* __restrict__ ln_w, const float* __restrict__ ln_b,
        const int* __restrict__ row_ptr,
        unsigned short* __restrict__ out, int N, int ostride) {
    constexpr int H = D / 64;
    constexpr int CPT = 8;
    constexpr int TPN = D / CPT;          // 32 (D=256) or 8 (D=64)
    constexpr int NPB = 256 / TPN;
    int tid = threadIdx.x;
    int n = blockIdx.x * NPB + tid / TPN;
    int t = tid % TPN;
    int c0 = CPT * t;
    int hh = c0 >> 6;
    if (n >= N) return;

    int rs = row_ptr[n], re = row_ptr[n + 1];
    float a[CPT] = {};
#pragma unroll 2
    for (int i = rs; i < re; ++i) {
        int2 r = rec[i * H + hh];
        float p = __int_as_float(r.y);
        uint4 u = *reinterpret_cast<const uint4*>(hbf + (size_t)r.x * D + c0);
        a[0] += p * bf2f(u.x & 0xffffu); a[1] += p * bf2f(u.x >> 16);
        a[2] += p * bf2f(u.y & 0xffffu); a[3] += p * bf2f(u.y >> 16);
        a[4] += p * bf2f(u.z & 0xffffu); a[5] += p * bf2f(u.z >> 16);
        a[6] += p * bf2f(u.w & 0xffffu); a[7] += p * bf2f(u.w >> 16);
    }
    float inv = 1.f / (sden[n * H + hh] + 1e-16f);
    float v[CPT];
    float sum = 0.f, sq = 0.f;
#pragma unroll
    for (int j = 0; j < CPT; ++j) {
        float w = a[j] * inv + bias[c0 + j];
        if (ELU) w = w > 0.f ? w : (__expf(w) - 1.f);
        v[j] = w;
        sum += w; sq += w * w;
    }
    // LN reduce across TPN lanes (within-wave group)
#pragma unroll
    for (int off = 1; off < TPN; off <<= 1) {
        sum += __shfl_xor(sum, off);
        sq += __shfl_xor(sq, off);
    }
    float mu = sum / D;
    float var = fmaxf(sq / D - mu * mu, 0.f);
    float rstd = rsqrtf(var + 1e-5f);
    uint4 o;
    unsigned int w01, w23, w45, w67;
    {
        float y0 = (v[0] - mu) * rstd * ln_w[c0 + 0] + ln_b[c0 + 0];
        float y1 = (v[1] - mu) * rstd * ln_w[c0 + 1] + ln_b[c0 + 1];
        w01 = (unsigned int)f2bf(y0) | ((unsigned int)f2bf(y1) << 16);
        float y2 = (v[2] - mu) * rstd * ln_w[c0 + 2] + ln_b[c0 + 2];
        float y3 = (v[3] - mu) * rstd * ln_w[c0 + 3] + ln_b[c0 + 3];
        w23 = (unsigned int)f2bf(y2) | ((unsigned int)f2bf(y3) << 16);
        float y4 = (v[4] - mu) * rstd * ln_w[c0 + 4] + ln_b[c0 + 4];
        float y5 = (v[5] - mu) * rstd * ln_w[c0 + 5] + ln_b[c0 + 5];
        w45 = (unsigned int)f2bf(y4) | ((unsigned int)f2bf(y5) << 16);
        float y6 = (v[6] - mu) * rstd * ln_w[c0 + 6] + ln_b[c0 + 6];
        float y7 = (v[7] - mu) * rstd * ln_w[c0 + 7] + ln_b[c0 + 7];
        w67 = (unsigned int)f2bf(y6) | ((unsigned int)f2bf(y7) << 16);
    }
    o.x = w01; o.y = w23; o.z = w45; o.w = w67;
    *reinterpret_cast<uint4*>(out + (size_t)n * ostride + c0) = o;
}

// ---------------- role embedding into bf16 concat buffer ----------------
__global__ void k_role(const int* __restrict__ role_ids,
                       const float* __restrict__ role_table,
                       unsigned short* __restrict__ catb, int N) {
    int i = blockIdx.x * 256 + threadIdx.x;
    int n = i >> 6, c = i & 63;
    if (n >= N) return;
    catb[(size_t)n * 128 + 64 + c] = f2bf(role_table[role_ids[n] * 64 + c]);
}

// ---------------------------------------------------------------------------
extern "C" void kernel_launch(void* const* d_in, const int* in_sizes, int n_in,
                              void* d_out, int out_size, void* d_ws, size_t ws_size,
                              hipStream_t stream) {
    const float* x        = (const float*)d_in[0];
    const int*   ei       = (const int*)d_in[1];
    const int*   role_ids = (const int*)d_in[2];
    const float* W1  = (const float*)d_in[3];
    const float* a1s = (const float*)d_in[4];
    const float* a1d = (const float*)d_in[5];
    const float* b1  = (const float*)d_in[6];
    const float* W2  = (const float*)d_in[7];
    const float* a2s = (const float*)d_in[8];
    const float* a2d = (const float*)d_in[9];
    const float* b2  = (const float*)d_in[10];
    const float* W3  = (const float*)d_in[11];
    const float* a3s = (const float*)d_in[12];
    const float* a3d = (const float*)d_in[13];
    const float* b3  = (const float*)d_in[14];
    const float* ln1w = (const float*)d_in[15];
    const float* ln1b = (const float*)d_in[16];
    const float* ln2w = (const float*)d_in[17];
    const float* ln2b = (const float*)d_in[18];
    const float* ln3w = (const float*)d_in[19];
    const float* ln3b = (const float*)d_in[20];
    const float* role_table = (const float*)d_in[21];
    const float* p1w = (const float*)d_in[22];
    const float* p1b = (const float*)d_in[23];
    const float* p2w = (const float*)d_in[24];
    const float* p2b = (const float*)d_in[25];

    const int N = in_sizes[0] / 64;
    const int E = in_sizes[1] / 2;
    const int E2 = E + N;

    // workspace carve
    char* p = (char*)d_ws;
    auto carve = [&](size_t bytes) -> char* {
        char* r = p;
        p += (bytes + 255) & ~(size_t)255;
        return r;
    };
    int* deg      = (int*)carve((size_t)N * 4);
    int* row_ptr  = (int*)carve((size_t)(N + 1) * 4);
    int* cursor   = (int*)carve((size_t)N * 4);
    int* edge_src = (int*)carve((size_t)E2 * 4);
    int* bsum     = (int*)carve((size_t)1024 * 4);
    int* boff     = (int*)carve((size_t)1024 * 4);
    float* sS     = (float*)carve((size_t)N * 4 * 4);
    float* sD     = (float*)carve((size_t)N * 4 * 4);
    int2* rec     = (int2*)carve((size_t)E2 * 4 * 8);
    float* sden   = (float*)carve((size_t)N * 4 * 4);
    unsigned short* hbf  = (unsigned short*)carve((size_t)N * 256 * 2);  // GEMM out (pre-agg)
    unsigned short* hlnb = (unsigned short*)carve((size_t)N * 256 * 2);  // LN out (next GEMM A)
    unsigned short* catb = (unsigned short*)carve((size_t)N * 128 * 2);
    unsigned short* z1b  = (unsigned short*)carve((size_t)N * 64 * 2);
    unsigned short* xb   = (unsigned short*)carve((size_t)N * 64 * 2);
    unsigned short* W1b  = (unsigned short*)carve((size_t)256 * 64 * 2);
    unsigned short* W2b  = (unsigned short*)carve((size_t)256 * 256 * 2);
    unsigned short* W3b  = (unsigned short*)carve((size_t)64 * 256 * 2);
    unsigned short* p1wb = (unsigned short*)carve((size_t)64 * 128 * 2);
    unsigned short* p2wb = (unsigned short*)carve((size_t)64 * 64 * 2);

    // ---- converts ----
    auto cvt = [&](const float* src, unsigned short* dst, int n) {
        k_f2bf<<<(n / 4 + 255) / 256, 256, 0, stream>>>(src, dst, n);
    };
    cvt(x, xb, N * 64);
    cvt(W1, W1b, 256 * 64);
    cvt(W2, W2b, 256 * 256);
    cvt(W3, W3b, 64 * 256);
    cvt(p1w, p1wb, 64 * 128);
    cvt(p2w, p2wb, 64 * 64);

    // ---- CSR build (parallel 3-kernel scan) ----
    hipMemsetAsync(deg, 0, (size_t)N * 4, stream);
    int eb = (E2 + 255) / 256;
    int nb = (N + 255) / 256;
    k_count<<<eb, 256, 0, stream>>>(ei, deg, N, E, E2);
    k_bsum<<<nb, 256, 0, stream>>>(deg, bsum, N);
    k_bscan<<<1, 256, 0, stream>>>(bsum, boff, nb);
    k_scatter<<<nb, 256, 0, stream>>>(deg, boff, row_ptr, cursor, N, E2);
    k_fill<<<eb, 256, 0, stream>>>(ei, cursor, edge_src, N, E, E2);

    int mb = (N + 127) / 128;

    // ---- layer 1: 64 -> 4x64 ----
    k_gmfma<64, 128, false, true><<<dim3(mb, 2), 256, 0, stream>>>(xb, W1b, nullptr, hbf, N, 256);
    k_scores<4><<<(N * 4 + 3) / 4, 256, 0, stream>>>(hbf, a1s, a1d, sS, sD, N);
    k_alpha<4><<<(N * 4 + 255) / 256, 256, 0, stream>>>(sS, sD, row_ptr, edge_src, rec, sden, N * 4);
    k_aggb<256, true><<<(N + 7) / 8, 256, 0, stream>>>(hbf, rec, sden, b1, ln1w, ln1b,
                                                       row_ptr, hlnb, N, 256);

    // ---- layer 2: 256 -> 4x64 ----
    k_gmfma<256, 128, false, true><<<dim3(mb, 2), 256, 0, stream>>>(hlnb, W2b, nullptr, hbf, N, 256);
    k_scores<4><<<(N * 4 + 3) / 4, 256, 0, stream>>>(hbf, a2s, a2d, sS, sD, N);
    k_alpha<4><<<(N * 4 + 255) / 256, 256, 0, stream>>>(sS, sD, row_ptr, edge_src, rec, sden, N * 4);
    k_aggb<256, true><<<(N + 7) / 8, 256, 0, stream>>>(hbf, rec, sden, b2, ln2w, ln2b,
                                                       row_ptr, hlnb, N, 256);

    // ---- layer 3: 256 -> 64 (1 head, no concat) ----
    k_gmfma<256, 64, false, true><<<dim3(mb, 1), 256, 0, stream>>>(hlnb, W3b, nullptr, hbf, N, 64);
    k_scores<1><<<(N + 3) / 4, 256, 0, stream>>>(hbf, a3s, a3d, sS, sD, N);
    k_alpha<1><<<(N + 255) / 256, 256, 0, stream>>>(sS, sD, row_ptr, edge_src, rec, sden, N);
    k_role<<<(N * 64 + 255) / 256, 256, 0, stream>>>(role_ids, role_table, catb, N);
    k_aggb<64, false><<<(N + 31) / 32, 256, 0, stream>>>(hbf, rec, sden, b3, ln3w, ln3b,
                                                         row_ptr, catb, N, 128);

    // ---- MLP: cat[N,128] -> relu -> [N,64] -> out ----
    k_gmfma<128, 64, true, true><<<dim3(mb, 1), 256, 0, stream>>>(catb, p1wb, p1b, z1b, N, 64);
    k_gmfma<64, 64, false, false><<<dim3(mb, 1), 256, 0, stream>>>(z1b, p2wb, p2b, (float*)d_out, N, 64);
}

// Round 7
// 356.456 us; speedup vs baseline: 3.0021x; 1.0552x over previous
//
#include <hip/hip_runtime.h>
#include <math.h>

// ---------------------------------------------------------------------------
// TopologyAwareGATEncoder: 3x GATConv(+ELU+LN) -> concat role emb -> 2-layer MLP
// N=50000, E=400000 (+N self loops), IN=64, HID=64, HEADS=4
// GEMMs via bf16 MFMA (16x16x32) with global_load_lds double-buffered staging.
// ---------------------------------------------------------------------------

using short8 = __attribute__((ext_vector_type(8))) short;
using f32x4  = __attribute__((ext_vector_type(4))) float;

__device__ __forceinline__ unsigned short f2bf(float f) {
    unsigned int u = __builtin_bit_cast(unsigned int, f);
    u += 0x7fffu + ((u >> 16) & 1u);     // RN-even
    return (unsigned short)(u >> 16);
}
__device__ __forceinline__ float bf2f(unsigned int b16) {
    unsigned int u = b16 << 16;
    return __builtin_bit_cast(float, u);
}

// ---------------- fp32 -> bf16 convert (n multiple of 4) ----------------
__global__ void k_f2bf(const float* __restrict__ in, unsigned short* __restrict__ out,
                       int n) {
    int i = (blockIdx.x * 256 + threadIdx.x) * 4;
    if (i >= n) return;
    float4 v = *reinterpret_cast<const float4*>(in + i);
    ushort4 u;
    u.x = f2bf(v.x); u.y = f2bf(v.y); u.z = f2bf(v.z); u.w = f2bf(v.w);
    *reinterpret_cast<ushort4*>(out + i) = u;
}

// ---------------- CSR build ----------------
__global__ void k_count(const int* __restrict__ ei, int* __restrict__ deg,
                        int N, int E, int E2) {
    int i = blockIdx.x * 256 + threadIdx.x;
    if (i >= E2) return;
    int d = (i < E) ? ei[E + i] : (i - E);
    atomicAdd(&deg[d], 1);
}

// block-wide inclusive scan of one int per thread (256 threads)
__device__ __forceinline__ int blk_scan_incl(int v, int tid) {
    int lane = tid & 63, w = tid >> 6;
#pragma unroll
    for (int off = 1; off < 64; off <<= 1) {
        int u = __shfl_up(v, off);
        if (lane >= off) v += u;
    }
    __shared__ int wsum[4];
    if (lane == 63) wsum[w] = v;
    __syncthreads();
    int add = 0;
#pragma unroll
    for (int k = 0; k < 4; ++k)
        if (k < w) add += wsum[k];
    return v + add;
}

__global__ __launch_bounds__(256) void k_bsum(const int* __restrict__ deg,
                                              int* __restrict__ bsum, int N) {
    int i = blockIdx.x * 256 + threadIdx.x;
    int v = (i < N) ? deg[i] : 0;
#pragma unroll
    for (int off = 32; off; off >>= 1) v += __shfl_down(v, off);
    __shared__ int ws[4];
    if ((threadIdx.x & 63) == 0) ws[threadIdx.x >> 6] = v;
    __syncthreads();
    if (threadIdx.x == 0) bsum[blockIdx.x] = ws[0] + ws[1] + ws[2] + ws[3];
}

__global__ __launch_bounds__(256) void k_bscan(const int* __restrict__ bsum,
                                               int* __restrict__ boff, int nb) {
    int t = threadIdx.x;
    int v = (t < nb) ? bsum[t] : 0;
    int incl = blk_scan_incl(v, t);
    if (t < nb) boff[t] = incl - v;      // exclusive
}

__global__ __launch_bounds__(256) void k_scatter(const int* __restrict__ deg,
                                                 const int* __restrict__ boff,
                                                 int* __restrict__ row_ptr,
                                                 int* __restrict__ cursor,
                                                 int N, int E2) {
    int tid = threadIdx.x;
    int i = blockIdx.x * 256 + tid;
    int d = (i < N) ? deg[i] : 0;
    int incl = blk_scan_incl(d, tid);
    int ex = incl - d + boff[blockIdx.x];
    if (i < N) { row_ptr[i] = ex; cursor[i] = ex; }
    if (i == 0) row_ptr[N] = E2;
}

__global__ void k_fill(const int* __restrict__ ei, int* __restrict__ cursor,
                       int* __restrict__ edge_src, int N, int E, int E2) {
    int i = blockIdx.x * 256 + threadIdx.x;
    if (i >= E2) return;
    int s_, d_;
    if (i < E) { s_ = ei[i]; d_ = ei[E + i]; }
    else       { s_ = d_ = i - E; }
    int pos = atomicAdd(&cursor[d_], 1);
    edge_src[pos] = s_;
}

// ---------------- bf16 MFMA GEMM: C[M,NC] = A[M,K] @ W[NC,K]^T --------------
// 128 x BN tile, BK=32, 256 thr = 4 waves (2m x 2n).
// Staging: global_load_lds width-16 direct DMA, linear LDS [row][32] (64B
// stride), double-buffered, ONE barrier per k-step (T3 minimum 2-phase):
//   STAGE(next) -> ds_read+MFMA(cur) -> barrier (vmcnt drain after compute).
template <int K, int BN, bool RELU, bool BF16OUT>
__global__ __launch_bounds__(256) void k_gmfma(const unsigned short* __restrict__ A,
                                               const unsigned short* __restrict__ Wb,
                                               const float* __restrict__ bias,
                                               void* __restrict__ Cv,
                                               int M, int NC) {
    constexpr int NT = BN / 32;           // n-frags per wave
    constexpr int NSTEP = K / 32;
    __shared__ unsigned short As[2][128 * 32];
    __shared__ unsigned short Bs[2][BN * 32];
    int tid = threadIdx.x;
    int lane = tid & 63, wid = tid >> 6;
    int wm = wid & 1, wn = wid >> 1;      // 2x2 wave grid
    int fr = lane & 15, fq = lane >> 4;
    int bm = blockIdx.x * 128, bn = blockIdx.y * BN;

    // per-lane source offsets for staging: lane covers row (lane>>2), k-chunk (lane&3)*8
    int lrow = lane >> 2, lkq = (lane & 3) * 8;

    auto stage = [&](int buf, int k0) {
#pragma unroll
        for (int i = 0; i < 2; ++i) {
            int ra = i * 64 + wid * 16;
            int row = bm + ra + lrow;
            row = min(row, M - 1);
            const unsigned short* gp = A + (size_t)row * K + k0 + lkq;
            __builtin_amdgcn_global_load_lds(
                (const __attribute__((address_space(1))) unsigned int*)gp,
                (__attribute__((address_space(3))) unsigned int*)&As[buf][ra * 32],
                16, 0, 0);
        }
#pragma unroll
        for (int i = 0; i < BN / 64; ++i) {
            int rb = i * 64 + wid * 16;
            const unsigned short* gp = Wb + (size_t)(bn + rb + lrow) * K + k0 + lkq;
            __builtin_amdgcn_global_load_lds(
                (const __attribute__((address_space(1))) unsigned int*)gp,
                (__attribute__((address_space(3))) unsigned int*)&Bs[buf][rb * 32],
                16, 0, 0);
        }
    };

    f32x4 acc[4][NT];
#pragma unroll
    for (int mt = 0; mt < 4; ++mt)
#pragma unroll
        for (int nt = 0; nt < NT; ++nt) acc[mt][nt] = f32x4{0.f, 0.f, 0.f, 0.f};

    stage(0, 0);
    __syncthreads();                      // drains vmcnt -> buf0 ready
    int cur = 0;
    for (int t = 0; t < NSTEP; ++t) {
        if (t + 1 < NSTEP) stage(cur ^ 1, (t + 1) * 32);   // loads in flight over MFMA
        short8 af[4], bfr[NT];
#pragma unroll
        for (int mt = 0; mt < 4; ++mt)
            af[mt] = *reinterpret_cast<const short8*>(
                &As[cur][(wm * 64 + mt * 16 + fr) * 32 + fq * 8]);
#pragma unroll
        for (int nt = 0; nt < NT; ++nt)
            bfr[nt] = *reinterpret_cast<const short8*>(
                &Bs[cur][(wn * (BN / 2) + nt * 16 + fr) * 32 + fq * 8]);
#pragma unroll
        for (int mt = 0; mt < 4; ++mt)
#pragma unroll
            for (int nt = 0; nt < NT; ++nt)
                acc[mt][nt] = __builtin_amdgcn_mfma_f32_16x16x32_bf16(
                    af[mt], bfr[nt], acc[mt][nt], 0, 0, 0);
        __syncthreads();                  // drain: next buf staged, cur free
        cur ^= 1;
    }

    // epilogue: C row = fq*4+j, col = fr within each 16x16 fragment
#pragma unroll
    for (int nt = 0; nt < NT; ++nt) {
        int col = bn + wn * (BN / 2) + nt * 16 + fr;
        float bv = bias ? bias[col] : 0.f;
#pragma unroll
        for (int mt = 0; mt < 4; ++mt) {
#pragma unroll
            for (int j = 0; j < 4; ++j) {
                int row = bm + wm * 64 + mt * 16 + fq * 4 + j;
                if (row < M) {
                    float v = acc[mt][nt][j] + bv;
                    if (RELU) v = fmaxf(v, 0.f);
                    if constexpr (BF16OUT)
                        ((unsigned short*)Cv)[(size_t)row * NC + col] = f2bf(v);
                    else
                        ((float*)Cv)[(size_t)row * NC + col] = v;
                }
            }
        }
    }
}

// ---------------- per-(node,head) attention scores (bf16 h) ----------------
template <int H>
__global__ __launch_bounds__(256) void k_scores(const unsigned short* __restrict__ h,
                                                const float* __restrict__ a_s,
                                                const float* __restrict__ a_d,
                                                float* __restrict__ sS,
                                                float* __restrict__ sD, int N) {
    int wid = threadIdx.x >> 6;
    int lane = threadIdx.x & 63;
    int gw = blockIdx.x * 4 + wid;
    if (gw >= N * H) return;
    int n = gw / H, hh = gw % H;
    float v = bf2f(h[(size_t)n * (H * 64) + hh * 64 + lane]);
    float ds = v * a_s[hh * 64 + lane];
    float dd = v * a_d[hh * 64 + lane];
#pragma unroll
    for (int off = 32; off; off >>= 1) {
        ds += __shfl_down(ds, off);
        dd += __shfl_down(dd, off);
    }
    if (lane == 0) { sS[n * H + hh] = ds; sD[n * H + hh] = dd; }
}

// -------- per-(node,head) softmax weights: rec = (src, p=exp(e-m)), sden ----
template <int H>
__global__ void k_alpha(const float* __restrict__ sS, const float* __restrict__ sD,
                        const int* __restrict__ row_ptr, const int* __restrict__ edge_src,
                        int2* __restrict__ rec, float* __restrict__ sden, int NH) {
    int gid = blockIdx.x * 256 + threadIdx.x;
    if (gid >= NH) return;
    int n = gid / H;
    int h = gid - n * H;
    float sdn = sD[gid];
    int rs = row_ptr[n], re = row_ptr[n + 1];
    float m = -1e30f;
    for (int i = rs; i < re; ++i) {
        int src = edge_src[i];
        float e = sS[src * H + h] + sdn;
        e = e > 0.f ? e : 0.2f * e;          // leaky_relu 0.2
        rec[i * H + h] = make_int2(src, __float_as_int(e));
        m = fmaxf(m, e);
    }
    float s = 0.f;
    for (int i = rs; i < re; ++i) {
        int2 r = rec[i * H + h];
        float p = __expf(__int_as_float(r.y) - m);
        rec[i * H + h].y = __float_as_int(p);
        s += p;
    }
    sden[gid] = s;
}

// ---------------- aggregation (bf16 gather) + bias + (ELU) + LayerNorm -----
// 8 channels/thread (uint4 gather). TPN = D/8 threads per node (32 or 8);
// LN reduction fits in a <=32-lane shuffle group: no LDS, no barrier.
template <int D, bool ELU>
__global__ __launch_bounds__(256) void k_aggb(
        const unsigned short* __restrict__ hbf,
        const int2* __restrict__ rec, const float* __restrict__ sden,
        const float* __restrict__ bias,
        const float* __restrict__ ln_w, const float* __restrict__ ln_b,
        const int* __restrict__ row_ptr,
        unsigned short* __restrict__ out, int N, int ostride) {
    constexpr int H = D / 64;
    constexpr int CPT = 8;
    constexpr int TPN = D / CPT;          // 32 (D=256) or 8 (D=64)
    constexpr int NPB = 256 / TPN;
    int tid = threadIdx.x;
    int n = blockIdx.x * NPB + tid / TPN;
    int t = tid % TPN;
    int c0 = CPT * t;
    int hh = c0 >> 6;
    if (n >= N) return;

    int rs = row_ptr[n], re = row_ptr[n + 1];
    float a[CPT] = {};
#pragma unroll 2
    for (int i = rs; i < re; ++i) {
        int2 r = rec[i * H + hh];
        float p = __int_as_float(r.y);
        uint4 u = *reinterpret_cast<const uint4*>(hbf + (size_t)r.x * D + c0);
        a[0] += p * bf2f(u.x & 0xffffu); a[1] += p * bf2f(u.x >> 16);
        a[2] += p * bf2f(u.y & 0xffffu); a[3] += p * bf2f(u.y >> 16);
        a[4] += p * bf2f(u.z & 0xffffu); a[5] += p * bf2f(u.z >> 16);
        a[6] += p * bf2f(u.w & 0xffffu); a[7] += p * bf2f(u.w >> 16);
    }
    float inv = 1.f / (sden[n * H + hh] + 1e-16f);
    float v[CPT];
    float sum = 0.f, sq = 0.f;
#pragma unroll
    for (int j = 0; j < CPT; ++j) {
        float w = a[j] * inv + bias[c0 + j];
        if (ELU) w = w > 0.f ? w : (__expf(w) - 1.f);
        v[j] = w;
        sum += w; sq += w * w;
    }
    // LN reduce across TPN lanes (within-wave group)
#pragma unroll
    for (int off = 1; off < TPN; off <<= 1) {
        sum += __shfl_xor(sum, off);
        sq += __shfl_xor(sq, off);
    }
    float mu = sum / D;
    float var = fmaxf(sq / D - mu * mu, 0.f);
    float rstd = rsqrtf(var + 1e-5f);
    uint4 o;
    unsigned int w01, w23, w45, w67;
    {
        float y0 = (v[0] - mu) * rstd * ln_w[c0 + 0] + ln_b[c0 + 0];
        float y1 = (v[1] - mu) * rstd * ln_w[c0 + 1] + ln_b[c0 + 1];
        w01 = (unsigned int)f2bf(y0) | ((unsigned int)f2bf(y1) << 16);
        float y2 = (v[2] - mu) * rstd * ln_w[c0 + 2] + ln_b[c0 + 2];
        float y3 = (v[3] - mu) * rstd * ln_w[c0 + 3] + ln_b[c0 + 3];
        w23 = (unsigned int)f2bf(y2) | ((unsigned int)f2bf(y3) << 16);
        float y4 = (v[4] - mu) * rstd * ln_w[c0 + 4] + ln_b[c0 + 4];
        float y5 = (v[5] - mu) * rstd * ln_w[c0 + 5] + ln_b[c0 + 5];
        w45 = (unsigned int)f2bf(y4) | ((unsigned int)f2bf(y5) << 16);
        float y6 = (v[6] - mu) * rstd * ln_w[c0 + 6] + ln_b[c0 + 6];
        float y7 = (v[7] - mu) * rstd * ln_w[c0 + 7] + ln_b[c0 + 7];
        w67 = (unsigned int)f2bf(y6) | ((unsigned int)f2bf(y7) << 16);
    }
    o.x = w01; o.y = w23; o.z = w45; o.w = w67;
    *reinterpret_cast<uint4*>(out + (size_t)n * ostride + c0) = o;
}

// ---------------- role embedding into bf16 concat buffer ----------------
__global__ void k_role(const int* __restrict__ role_ids,
                       const float* __restrict__ role_table,
                       unsigned short* __restrict__ catb, int N) {
    int i = blockIdx.x * 256 + threadIdx.x;
    int n = i >> 6, c = i & 63;
    if (n >= N) return;
    catb[(size_t)n * 128 + 64 + c] = f2bf(role_table[role_ids[n] * 64 + c]);
}

// ---------------------------------------------------------------------------
extern "C" void kernel_launch(void* const* d_in, const int* in_sizes, int n_in,
                              void* d_out, int out_size, void* d_ws, size_t ws_size,
                              hipStream_t stream) {
    const float* x        = (const float*)d_in[0];
    const int*   ei       = (const int*)d_in[1];
    const int*   role_ids = (const int*)d_in[2];
    const float* W1  = (const float*)d_in[3];
    const float* a1s = (const float*)d_in[4];
    const float* a1d = (const float*)d_in[5];
    const float* b1  = (const float*)d_in[6];
    const float* W2  = (const float*)d_in[7];
    const float* a2s = (const float*)d_in[8];
    const float* a2d = (const float*)d_in[9];
    const float* b2  = (const float*)d_in[10];
    const float* W3  = (const float*)d_in[11];
    const float* a3s = (const float*)d_in[12];
    const float* a3d = (const float*)d_in[13];
    const float* b3  = (const float*)d_in[14];
    const float* ln1w = (const float*)d_in[15];
    const float* ln1b = (const float*)d_in[16];
    const float* ln2w = (const float*)d_in[17];
    const float* ln2b = (const float*)d_in[18];
    const float* ln3w = (const float*)d_in[19];
    const float* ln3b = (const float*)d_in[20];
    const float* role_table = (const float*)d_in[21];
    const float* p1w = (const float*)d_in[22];
    const float* p1b = (const float*)d_in[23];
    const float* p2w = (const float*)d_in[24];
    const float* p2b = (const float*)d_in[25];

    const int N = in_sizes[0] / 64;
    const int E = in_sizes[1] / 2;
    const int E2 = E + N;

    // workspace carve
    char* p = (char*)d_ws;
    auto carve = [&](size_t bytes) -> char* {
        char* r = p;
        p += (bytes + 255) & ~(size_t)255;
        return r;
    };
    int* deg      = (int*)carve((size_t)N * 4);
    int* row_ptr  = (int*)carve((size_t)(N + 1) * 4);
    int* cursor   = (int*)carve((size_t)N * 4);
    int* edge_src = (int*)carve((size_t)E2 * 4);
    int* bsum     = (int*)carve((size_t)1024 * 4);
    int* boff     = (int*)carve((size_t)1024 * 4);
    float* sS     = (float*)carve((size_t)N * 4 * 4);
    float* sD     = (float*)carve((size_t)N * 4 * 4);
    int2* rec     = (int2*)carve((size_t)E2 * 4 * 8);
    float* sden   = (float*)carve((size_t)N * 4 * 4);
    unsigned short* hbf  = (unsigned short*)carve((size_t)N * 256 * 2);  // GEMM out (pre-agg)
    unsigned short* hlnb = (unsigned short*)carve((size_t)N * 256 * 2);  // LN out (next GEMM A)
    unsigned short* catb = (unsigned short*)carve((size_t)N * 128 * 2);
    unsigned short* z1b  = (unsigned short*)carve((size_t)N * 64 * 2);
    unsigned short* xb   = (unsigned short*)carve((size_t)N * 64 * 2);
    unsigned short* W1b  = (unsigned short*)carve((size_t)256 * 64 * 2);
    unsigned short* W2b  = (unsigned short*)carve((size_t)256 * 256 * 2);
    unsigned short* W3b  = (unsigned short*)carve((size_t)64 * 256 * 2);
    unsigned short* p1wb = (unsigned short*)carve((size_t)64 * 128 * 2);
    unsigned short* p2wb = (unsigned short*)carve((size_t)64 * 64 * 2);

    // ---- converts ----
    auto cvt = [&](const float* src, unsigned short* dst, int n) {
        k_f2bf<<<(n / 4 + 255) / 256, 256, 0, stream>>>(src, dst, n);
    };
    cvt(x, xb, N * 64);
    cvt(W1, W1b, 256 * 64);
    cvt(W2, W2b, 256 * 256);
    cvt(W3, W3b, 64 * 256);
    cvt(p1w, p1wb, 64 * 128);
    cvt(p2w, p2wb, 64 * 64);

    // ---- CSR build (parallel 3-kernel scan) ----
    hipMemsetAsync(deg, 0, (size_t)N * 4, stream);
    int eb = (E2 + 255) / 256;
    int nb = (N + 255) / 256;
    k_count<<<eb, 256, 0, stream>>>(ei, deg, N, E, E2);
    k_bsum<<<nb, 256, 0, stream>>>(deg, bsum, N);
    k_bscan<<<1, 256, 0, stream>>>(bsum, boff, nb);
    k_scatter<<<nb, 256, 0, stream>>>(deg, boff, row_ptr, cursor, N, E2);
    k_fill<<<eb, 256, 0, stream>>>(ei, cursor, edge_src, N, E, E2);

    int mb = (N + 127) / 128;

    // ---- layer 1: 64 -> 4x64 ----
    k_gmfma<64, 128, false, true><<<dim3(mb, 2), 256, 0, stream>>>(xb, W1b, nullptr, hbf, N, 256);
    k_scores<4><<<(N * 4 + 3) / 4, 256, 0, stream>>>(hbf, a1s, a1d, sS, sD, N);
    k_alpha<4><<<(N * 4 + 255) / 256, 256, 0, stream>>>(sS, sD, row_ptr, edge_src, rec, sden, N * 4);
    k_aggb<256, true><<<(N + 7) / 8, 256, 0, stream>>>(hbf, rec, sden, b1, ln1w, ln1b,
                                                       row_ptr, hlnb, N, 256);

    // ---- layer 2: 256 -> 4x64 ----
    k_gmfma<256, 128, false, true><<<dim3(mb, 2), 256, 0, stream>>>(hlnb, W2b, nullptr, hbf, N, 256);
    k_scores<4><<<(N * 4 + 3) / 4, 256, 0, stream>>>(hbf, a2s, a2d, sS, sD, N);
    k_alpha<4><<<(N * 4 + 255) / 256, 256, 0, stream>>>(sS, sD, row_ptr, edge_src, rec, sden, N * 4);
    k_aggb<256, true><<<(N + 7) / 8, 256, 0, stream>>>(hbf, rec, sden, b2, ln2w, ln2b,
                                                       row_ptr, hlnb, N, 256);

    // ---- layer 3: 256 -> 64 (1 head, no concat) ----
    k_gmfma<256, 64, false, true><<<dim3(mb, 1), 256, 0, stream>>>(hlnb, W3b, nullptr, hbf, N, 64);
    k_scores<1><<<(N + 3) / 4, 256, 0, stream>>>(hbf, a3s, a3d, sS, sD, N);
    k_alpha<1><<<(N + 255) / 256, 256, 0, stream>>>(sS, sD, row_ptr, edge_src, rec, sden, N);
    k_role<<<(N * 64 + 255) / 256, 256, 0, stream>>>(role_ids, role_table, catb, N);
    k_aggb<64, false><<<(N + 31) / 32, 256, 0, stream>>>(hbf, rec, sden, b3, ln3w, ln3b,
                                                         row_ptr, catb, N, 128);

    // ---- MLP: cat[N,128] -> relu -> [N,64] -> out ----
    k_gmfma<128, 64, true, true><<<dim3(mb, 1), 256, 0, stream>>>(catb, p1wb, p1b, z1b, N, 64);
    k_gmfma<64, 64, false, false><<<dim3(mb, 1), 256, 0, stream>>>(z1b, p2wb, p2b, (float*)d_out, N, 64);
}

// Round 8
// 316.066 us; speedup vs baseline: 3.3857x; 1.1278x over previous
//
#include <hip/hip_runtime.h>
#include <math.h>

// ---------------------------------------------------------------------------
// TopologyAwareGATEncoder: 3x GATConv(+ELU+LN) -> concat role emb -> 2-layer MLP
// N=50000, E=400000 (+N self loops), IN=64, HID=64, HEADS=4
// GEMMs via bf16 MFMA (16x16x32) with global_load_lds double-buffered staging.
// Aggregation: fused online-softmax (flash-style) + bf16 gather + ELU + LN.
// ---------------------------------------------------------------------------

using short8 = __attribute__((ext_vector_type(8))) short;
using f32x4  = __attribute__((ext_vector_type(4))) float;

__device__ __forceinline__ unsigned short f2bf(float f) {
    unsigned int u = __builtin_bit_cast(unsigned int, f);
    u += 0x7fffu + ((u >> 16) & 1u);     // RN-even
    return (unsigned short)(u >> 16);
}
__device__ __forceinline__ float bf2f(unsigned int b16) {
    unsigned int u = b16 << 16;
    return __builtin_bit_cast(float, u);
}

// ---------------- fp32 -> bf16 convert (n multiple of 4) ----------------
__global__ void k_f2bf(const float* __restrict__ in, unsigned short* __restrict__ out,
                       int n) {
    int i = (blockIdx.x * 256 + threadIdx.x) * 4;
    if (i >= n) return;
    float4 v = *reinterpret_cast<const float4*>(in + i);
    ushort4 u;
    u.x = f2bf(v.x); u.y = f2bf(v.y); u.z = f2bf(v.z); u.w = f2bf(v.w);
    *reinterpret_cast<ushort4*>(out + i) = u;
}

// ---------------- CSR build ----------------
__global__ void k_count(const int* __restrict__ ei, int* __restrict__ deg,
                        int N, int E, int E2) {
    int i = blockIdx.x * 256 + threadIdx.x;
    if (i >= E2) return;
    int d = (i < E) ? ei[E + i] : (i - E);
    atomicAdd(&deg[d], 1);
}

// block-wide inclusive scan of one int per thread (256 threads)
__device__ __forceinline__ int blk_scan_incl(int v, int tid) {
    int lane = tid & 63, w = tid >> 6;
#pragma unroll
    for (int off = 1; off < 64; off <<= 1) {
        int u = __shfl_up(v, off);
        if (lane >= off) v += u;
    }
    __shared__ int wsum[4];
    if (lane == 63) wsum[w] = v;
    __syncthreads();
    int add = 0;
#pragma unroll
    for (int k = 0; k < 4; ++k)
        if (k < w) add += wsum[k];
    return v + add;
}

__global__ __launch_bounds__(256) void k_bsum(const int* __restrict__ deg,
                                              int* __restrict__ bsum, int N) {
    int i = blockIdx.x * 256 + threadIdx.x;
    int v = (i < N) ? deg[i] : 0;
#pragma unroll
    for (int off = 32; off; off >>= 1) v += __shfl_down(v, off);
    __shared__ int ws[4];
    if ((threadIdx.x & 63) == 0) ws[threadIdx.x >> 6] = v;
    __syncthreads();
    if (threadIdx.x == 0) bsum[blockIdx.x] = ws[0] + ws[1] + ws[2] + ws[3];
}

__global__ __launch_bounds__(256) void k_bscan(const int* __restrict__ bsum,
                                               int* __restrict__ boff, int nb) {
    int t = threadIdx.x;
    int v = (t < nb) ? bsum[t] : 0;
    int incl = blk_scan_incl(v, t);
    if (t < nb) boff[t] = incl - v;      // exclusive
}

__global__ __launch_bounds__(256) void k_scatter(const int* __restrict__ deg,
                                                 const int* __restrict__ boff,
                                                 int* __restrict__ row_ptr,
                                                 int* __restrict__ cursor,
                                                 int N, int E2) {
    int tid = threadIdx.x;
    int i = blockIdx.x * 256 + tid;
    int d = (i < N) ? deg[i] : 0;
    int incl = blk_scan_incl(d, tid);
    int ex = incl - d + boff[blockIdx.x];
    if (i < N) { row_ptr[i] = ex; cursor[i] = ex; }
    if (i == 0) row_ptr[N] = E2;
}

__global__ void k_fill(const int* __restrict__ ei, int* __restrict__ cursor,
                       int* __restrict__ edge_src, int N, int E, int E2) {
    int i = blockIdx.x * 256 + threadIdx.x;
    if (i >= E2) return;
    int s_, d_;
    if (i < E) { s_ = ei[i]; d_ = ei[E + i]; }
    else       { s_ = d_ = i - E; }
    int pos = atomicAdd(&cursor[d_], 1);
    edge_src[pos] = s_;
}

// ---------------- bf16 MFMA GEMM: C[M,NC] = A[M,K] @ W[NC,K]^T --------------
// 128 x BN tile, BK=32, 256 thr = 4 waves (2m x 2n).
// Staging: global_load_lds width-16 direct DMA, linear LDS [row][32] (64B
// stride), double-buffered, ONE barrier per k-step.
template <int K, int BN, bool RELU, bool BF16OUT>
__global__ __launch_bounds__(256) void k_gmfma(const unsigned short* __restrict__ A,
                                               const unsigned short* __restrict__ Wb,
                                               const float* __restrict__ bias,
                                               void* __restrict__ Cv,
                                               int M, int NC) {
    constexpr int NT = BN / 32;           // n-frags per wave
    constexpr int NSTEP = K / 32;
    __shared__ unsigned short As[2][128 * 32];
    __shared__ unsigned short Bs[2][BN * 32];
    int tid = threadIdx.x;
    int lane = tid & 63, wid = tid >> 6;
    int wm = wid & 1, wn = wid >> 1;      // 2x2 wave grid
    int fr = lane & 15, fq = lane >> 4;
    int bm = blockIdx.x * 128, bn = blockIdx.y * BN;

    // per-lane source offsets for staging: lane covers row (lane>>2), k-chunk (lane&3)*8
    int lrow = lane >> 2, lkq = (lane & 3) * 8;

    auto stage = [&](int buf, int k0) {
#pragma unroll
        for (int i = 0; i < 2; ++i) {
            int ra = i * 64 + wid * 16;
            int row = bm + ra + lrow;
            row = min(row, M - 1);
            const unsigned short* gp = A + (size_t)row * K + k0 + lkq;
            __builtin_amdgcn_global_load_lds(
                (const __attribute__((address_space(1))) unsigned int*)gp,
                (__attribute__((address_space(3))) unsigned int*)&As[buf][ra * 32],
                16, 0, 0);
        }
#pragma unroll
        for (int i = 0; i < BN / 64; ++i) {
            int rb = i * 64 + wid * 16;
            const unsigned short* gp = Wb + (size_t)(bn + rb + lrow) * K + k0 + lkq;
            __builtin_amdgcn_global_load_lds(
                (const __attribute__((address_space(1))) unsigned int*)gp,
                (__attribute__((address_space(3))) unsigned int*)&Bs[buf][rb * 32],
                16, 0, 0);
        }
    };

    f32x4 acc[4][NT];
#pragma unroll
    for (int mt = 0; mt < 4; ++mt)
#pragma unroll
        for (int nt = 0; nt < NT; ++nt) acc[mt][nt] = f32x4{0.f, 0.f, 0.f, 0.f};

    stage(0, 0);
    __syncthreads();                      // drains vmcnt -> buf0 ready
    int cur = 0;
    for (int t = 0; t < NSTEP; ++t) {
        if (t + 1 < NSTEP) stage(cur ^ 1, (t + 1) * 32);   // loads in flight over MFMA
        short8 af[4], bfr[NT];
#pragma unroll
        for (int mt = 0; mt < 4; ++mt)
            af[mt] = *reinterpret_cast<const short8*>(
                &As[cur][(wm * 64 + mt * 16 + fr) * 32 + fq * 8]);
#pragma unroll
        for (int nt = 0; nt < NT; ++nt)
            bfr[nt] = *reinterpret_cast<const short8*>(
                &Bs[cur][(wn * (BN / 2) + nt * 16 + fr) * 32 + fq * 8]);
#pragma unroll
        for (int mt = 0; mt < 4; ++mt)
#pragma unroll
            for (int nt = 0; nt < NT; ++nt)
                acc[mt][nt] = __builtin_amdgcn_mfma_f32_16x16x32_bf16(
                    af[mt], bfr[nt], acc[mt][nt], 0, 0, 0);
        __syncthreads();                  // drain: next buf staged, cur free
        cur ^= 1;
    }

    // epilogue: C row = fq*4+j, col = fr within each 16x16 fragment
#pragma unroll
    for (int nt = 0; nt < NT; ++nt) {
        int col = bn + wn * (BN / 2) + nt * 16 + fr;
        float bv = bias ? bias[col] : 0.f;
#pragma unroll
        for (int mt = 0; mt < 4; ++mt) {
#pragma unroll
            for (int j = 0; j < 4; ++j) {
                int row = bm + wm * 64 + mt * 16 + fq * 4 + j;
                if (row < M) {
                    float v = acc[mt][nt][j] + bv;
                    if (RELU) v = fmaxf(v, 0.f);
                    if constexpr (BF16OUT)
                        ((unsigned short*)Cv)[(size_t)row * NC + col] = f2bf(v);
                    else
                        ((float*)Cv)[(size_t)row * NC + col] = v;
                }
            }
        }
    }
}

// ---------------- per-(node,head) attention scores (bf16 h) ----------------
template <int H>
__global__ __launch_bounds__(256) void k_scores(const unsigned short* __restrict__ h,
                                                const float* __restrict__ a_s,
                                                const float* __restrict__ a_d,
                                                float* __restrict__ sS,
                                                float* __restrict__ sD, int N) {
    int wid = threadIdx.x >> 6;
    int lane = threadIdx.x & 63;
    int gw = blockIdx.x * 4 + wid;
    if (gw >= N * H) return;
    int n = gw / H, hh = gw % H;
    float v = bf2f(h[(size_t)n * (H * 64) + hh * 64 + lane]);
    float ds = v * a_s[hh * 64 + lane];
    float dd = v * a_d[hh * 64 + lane];
#pragma unroll
    for (int off = 32; off; off >>= 1) {
        ds += __shfl_down(ds, off);
        dd += __shfl_down(dd, off);
    }
    if (lane == 0) { sS[n * H + hh] = ds; sD[n * H + hh] = dd; }
}

// ------- fused aggregation: online softmax + bf16 gather + (ELU) + LN ------
// Phase 1: TPN lanes stride the edge list, online (m,s) per head in regs,
//          shuffle-butterfly combine (no intermediate alpha buffer).
// Phase 2: gather loop computes p = exp(leaky(sS[src]+sD[n]) - m) inline.
template <int D, bool ELU>
__global__ __launch_bounds__(256) void k_agg2(
        const unsigned short* __restrict__ hbf,
        const float* __restrict__ sS, const float* __restrict__ sD,
        const float* __restrict__ bias,
        const float* __restrict__ ln_w, const float* __restrict__ ln_b,
        const int* __restrict__ row_ptr, const int* __restrict__ edge_src,
        unsigned short* __restrict__ out, int N, int ostride) {
    constexpr int H = D / 64;
    constexpr int CPT = 8;
    constexpr int TPN = D / CPT;          // 32 (D=256) or 8 (D=64)
    constexpr int NPB = 256 / TPN;
    int tid = threadIdx.x;
    int n = blockIdx.x * NPB + tid / TPN;
    int t = tid % TPN;
    if (n >= N) return;
    int rs = row_ptr[n], re = row_ptr[n + 1];

    float sd[H];
    if constexpr (H == 4) {
        float4 s4 = *reinterpret_cast<const float4*>(sD + (size_t)n * 4);
        sd[0] = s4.x; sd[1] = s4.y; sd[2] = s4.z; sd[3] = s4.w;
    } else {
        sd[0] = sD[n];
    }

    // ---- phase 1: online softmax stats, lanes stride edges ----
    float m[H], s[H];
#pragma unroll
    for (int h = 0; h < H; ++h) { m[h] = -1e30f; s[h] = 0.f; }
    for (int i = rs + t; i < re; i += TPN) {
        int src = edge_src[i];
        float ev[H];
        if constexpr (H == 4) {
            float4 s4 = *reinterpret_cast<const float4*>(sS + (size_t)src * 4);
            ev[0] = s4.x; ev[1] = s4.y; ev[2] = s4.z; ev[3] = s4.w;
        } else {
            ev[0] = sS[src];
        }
#pragma unroll
        for (int h = 0; h < H; ++h) {
            float e = ev[h] + sd[h];
            e = e > 0.f ? e : 0.2f * e;
            float mn = fmaxf(m[h], e);
            s[h] = s[h] * __expf(m[h] - mn) + __expf(e - mn);
            m[h] = mn;
        }
    }
#pragma unroll
    for (int off = 1; off < TPN; off <<= 1) {
#pragma unroll
        for (int h = 0; h < H; ++h) {
            float mo = __shfl_xor(m[h], off);
            float so = __shfl_xor(s[h], off);
            float mn = fmaxf(m[h], mo);
            s[h] = s[h] * __expf(m[h] - mn) + so * __expf(mo - mn);
            m[h] = mn;
        }
    }

    // ---- phase 2: weighted gather, 8 channels/thread ----
    int c0 = CPT * t;
    int hh = c0 >> 6;
    float mh = m[hh];
    float inv = 1.f / (s[hh] + 1e-16f);
    float sdn = sd[hh];
    float a[CPT] = {};
#pragma unroll 2
    for (int i = rs; i < re; ++i) {
        int src = edge_src[i];
        float e = sS[(size_t)src * H + hh] + sdn;
        e = e > 0.f ? e : 0.2f * e;
        float p = __expf(e - mh);
        uint4 u = *reinterpret_cast<const uint4*>(hbf + (size_t)src * D + c0);
        a[0] += p * bf2f(u.x & 0xffffu); a[1] += p * bf2f(u.x >> 16);
        a[2] += p * bf2f(u.y & 0xffffu); a[3] += p * bf2f(u.y >> 16);
        a[4] += p * bf2f(u.z & 0xffffu); a[5] += p * bf2f(u.z >> 16);
        a[6] += p * bf2f(u.w & 0xffffu); a[7] += p * bf2f(u.w >> 16);
    }
    float v[CPT];
    float sum = 0.f, sq = 0.f;
#pragma unroll
    for (int j = 0; j < CPT; ++j) {
        float w = a[j] * inv + bias[c0 + j];
        if (ELU) w = w > 0.f ? w : (__expf(w) - 1.f);
        v[j] = w;
        sum += w; sq += w * w;
    }
    // LN reduce across TPN lanes (within-wave group)
#pragma unroll
    for (int off = 1; off < TPN; off <<= 1) {
        sum += __shfl_xor(sum, off);
        sq += __shfl_xor(sq, off);
    }
    float mu = sum / D;
    float var = fmaxf(sq / D - mu * mu, 0.f);
    float rstd = rsqrtf(var + 1e-5f);
    unsigned int w01, w23, w45, w67;
    {
        float y0 = (v[0] - mu) * rstd * ln_w[c0 + 0] + ln_b[c0 + 0];
        float y1 = (v[1] - mu) * rstd * ln_w[c0 + 1] + ln_b[c0 + 1];
        w01 = (unsigned int)f2bf(y0) | ((unsigned int)f2bf(y1) << 16);
        float y2 = (v[2] - mu) * rstd * ln_w[c0 + 2] + ln_b[c0 + 2];
        float y3 = (v[3] - mu) * rstd * ln_w[c0 + 3] + ln_b[c0 + 3];
        w23 = (unsigned int)f2bf(y2) | ((unsigned int)f2bf(y3) << 16);
        float y4 = (v[4] - mu) * rstd * ln_w[c0 + 4] + ln_b[c0 + 4];
        float y5 = (v[5] - mu) * rstd * ln_w[c0 + 5] + ln_b[c0 + 5];
        w45 = (unsigned int)f2bf(y4) | ((unsigned int)f2bf(y5) << 16);
        float y6 = (v[6] - mu) * rstd * ln_w[c0 + 6] + ln_b[c0 + 6];
        float y7 = (v[7] - mu) * rstd * ln_w[c0 + 7] + ln_b[c0 + 7];
        w67 = (unsigned int)f2bf(y6) | ((unsigned int)f2bf(y7) << 16);
    }
    uint4 o;
    o.x = w01; o.y = w23; o.z = w45; o.w = w67;
    *reinterpret_cast<uint4*>(out + (size_t)n * ostride + c0) = o;
}

// ---------------- role embedding into bf16 concat buffer ----------------
__global__ void k_role(const int* __restrict__ role_ids,
                       const float* __restrict__ role_table,
                       unsigned short* __restrict__ catb, int N) {
    int i = blockIdx.x * 256 + threadIdx.x;
    int n = i >> 6, c = i & 63;
    if (n >= N) return;
    catb[(size_t)n * 128 + 64 + c] = f2bf(role_table[role_ids[n] * 64 + c]);
}

// ---------------------------------------------------------------------------
extern "C" void kernel_launch(void* const* d_in, const int* in_sizes, int n_in,
                              void* d_out, int out_size, void* d_ws, size_t ws_size,
                              hipStream_t stream) {
    const float* x        = (const float*)d_in[0];
    const int*   ei       = (const int*)d_in[1];
    const int*   role_ids = (const int*)d_in[2];
    const float* W1  = (const float*)d_in[3];
    const float* a1s = (const float*)d_in[4];
    const float* a1d = (const float*)d_in[5];
    const float* b1  = (const float*)d_in[6];
    const float* W2  = (const float*)d_in[7];
    const float* a2s = (const float*)d_in[8];
    const float* a2d = (const float*)d_in[9];
    const float* b2  = (const float*)d_in[10];
    const float* W3  = (const float*)d_in[11];
    const float* a3s = (const float*)d_in[12];
    const float* a3d = (const float*)d_in[13];
    const float* b3  = (const float*)d_in[14];
    const float* ln1w = (const float*)d_in[15];
    const float* ln1b = (const float*)d_in[16];
    const float* ln2w = (const float*)d_in[17];
    const float* ln2b = (const float*)d_in[18];
    const float* ln3w = (const float*)d_in[19];
    const float* ln3b = (const float*)d_in[20];
    const float* role_table = (const float*)d_in[21];
    const float* p1w = (const float*)d_in[22];
    const float* p1b = (const float*)d_in[23];
    const float* p2w = (const float*)d_in[24];
    const float* p2b = (const float*)d_in[25];

    const int N = in_sizes[0] / 64;
    const int E = in_sizes[1] / 2;
    const int E2 = E + N;

    // workspace carve
    char* p = (char*)d_ws;
    auto carve = [&](size_t bytes) -> char* {
        char* r = p;
        p += (bytes + 255) & ~(size_t)255;
        return r;
    };
    int* deg      = (int*)carve((size_t)N * 4);
    int* row_ptr  = (int*)carve((size_t)(N + 1) * 4);
    int* cursor   = (int*)carve((size_t)N * 4);
    int* edge_src = (int*)carve((size_t)E2 * 4);
    int* bsum     = (int*)carve((size_t)1024 * 4);
    int* boff     = (int*)carve((size_t)1024 * 4);
    float* sS     = (float*)carve((size_t)N * 4 * 4);
    float* sD     = (float*)carve((size_t)N * 4 * 4);
    unsigned short* hbf  = (unsigned short*)carve((size_t)N * 256 * 2);  // GEMM out (pre-agg)
    unsigned short* hlnb = (unsigned short*)carve((size_t)N * 256 * 2);  // LN out (next GEMM A)
    unsigned short* catb = (unsigned short*)carve((size_t)N * 128 * 2);
    unsigned short* z1b  = (unsigned short*)carve((size_t)N * 64 * 2);
    unsigned short* xb   = (unsigned short*)carve((size_t)N * 64 * 2);
    unsigned short* W1b  = (unsigned short*)carve((size_t)256 * 64 * 2);
    unsigned short* W2b  = (unsigned short*)carve((size_t)256 * 256 * 2);
    unsigned short* W3b  = (unsigned short*)carve((size_t)64 * 256 * 2);
    unsigned short* p1wb = (unsigned short*)carve((size_t)64 * 128 * 2);
    unsigned short* p2wb = (unsigned short*)carve((size_t)64 * 64 * 2);

    // ---- converts ----
    auto cvt = [&](const float* src, unsigned short* dst, int n) {
        k_f2bf<<<(n / 4 + 255) / 256, 256, 0, stream>>>(src, dst, n);
    };
    cvt(x, xb, N * 64);
    cvt(W1, W1b, 256 * 64);
    cvt(W2, W2b, 256 * 256);
    cvt(W3, W3b, 64 * 256);
    cvt(p1w, p1wb, 64 * 128);
    cvt(p2w, p2wb, 64 * 64);

    // ---- CSR build (parallel 3-kernel scan) ----
    hipMemsetAsync(deg, 0, (size_t)N * 4, stream);
    int eb = (E2 + 255) / 256;
    int nb = (N + 255) / 256;
    k_count<<<eb, 256, 0, stream>>>(ei, deg, N, E, E2);
    k_bsum<<<nb, 256, 0, stream>>>(deg, bsum, N);
    k_bscan<<<1, 256, 0, stream>>>(bsum, boff, nb);
    k_scatter<<<nb, 256, 0, stream>>>(deg, boff, row_ptr, cursor, N, E2);
    k_fill<<<eb, 256, 0, stream>>>(ei, cursor, edge_src, N, E, E2);

    int mb = (N + 127) / 128;

    // ---- layer 1: 64 -> 4x64 ----
    k_gmfma<64, 128, false, true><<<dim3(mb, 2), 256, 0, stream>>>(xb, W1b, nullptr, hbf, N, 256);
    k_scores<4><<<(N * 4 + 3) / 4, 256, 0, stream>>>(hbf, a1s, a1d, sS, sD, N);
    k_agg2<256, true><<<(N + 7) / 8, 256, 0, stream>>>(hbf, sS, sD, b1, ln1w, ln1b,
                                                       row_ptr, edge_src, hlnb, N, 256);

    // ---- layer 2: 256 -> 4x64 ----
    k_gmfma<256, 128, false, true><<<dim3(mb, 2), 256, 0, stream>>>(hlnb, W2b, nullptr, hbf, N, 256);
    k_scores<4><<<(N * 4 + 3) / 4, 256, 0, stream>>>(hbf, a2s, a2d, sS, sD, N);
    k_agg2<256, true><<<(N + 7) / 8, 256, 0, stream>>>(hbf, sS, sD, b2, ln2w, ln2b,
                                                       row_ptr, edge_src, hlnb, N, 256);

    // ---- layer 3: 256 -> 64 (1 head, no concat) ----
    k_gmfma<256, 64, false, true><<<dim3(mb, 1), 256, 0, stream>>>(hlnb, W3b, nullptr, hbf, N, 64);
    k_scores<1><<<(N + 3) / 4, 256, 0, stream>>>(hbf, a3s, a3d, sS, sD, N);
    k_role<<<(N * 64 + 255) / 256, 256, 0, stream>>>(role_ids, role_table, catb, N);
    k_agg2<64, false><<<(N + 31) / 32, 256, 0, stream>>>(hbf, sS, sD, b3, ln3w, ln3b,
                                                         row_ptr, edge_src, catb, N, 128);

    // ---- MLP: cat[N,128] -> relu -> [N,64] -> out ----
    k_gmfma<128, 64, true, true><<<dim3(mb, 1), 256, 0, stream>>>(catb, p1wb, p1b, z1b, N, 64);
    k_gmfma<64, 64, false, false><<<dim3(mb, 1), 256, 0, stream>>>(z1b, p2wb, p2b, (float*)d_out, N, 64);
}